// Round 15
// baseline (345.468 us; speedup 1.0000x reference)
//
#include <hip/hip_runtime.h>
#include <math.h>

#define B_ 4
#define C_ 200
#define W_ 300
#define WP_ 304          // padded W for bf16x8 rows
#define H_ 128
#define NH_ 8
#define PH_ 16
#define FF_ 512
#define L_ 2
#define MAXLEN_ 200
#define PEN_ 512
#define WVS_ 136         // LDS B-matrix row stride (bf16): 2-way-free banks, 16B aligned

typedef __bf16 bf16x8 __attribute__((ext_vector_type(8)));
typedef float f32x4v __attribute__((ext_vector_type(4)));

// prep grid segments
#define SEG_KV   (PEN_)                    // 512
#define SEG_CVT  (PEN_ + L_ * B_ * W_)     // 2912
#define N_WR_BLK   256                     // L*H*H/128
#define N_W1_BLK  1024                     // L*FF*H/128
#define N_W2_BLK  1024
#define PREP_BLOCKS (SEG_CVT + N_WR_BLK + N_W1_BLK + N_W2_BLK)   // 5216

// ---------------- prep: PEW(bf16, bias folded) | kb(bf16)/vT(bf16) | weight converts
__global__ __launch_bounds__(128) void prep_kernel(
        const float* __restrict__ Wf, const float* __restrict__ bfv,
        const float* __restrict__ words,
        const float* __restrict__ Wk, const float* __restrict__ bk,
        const float* __restrict__ Wv, const float* __restrict__ bv,
        const float* __restrict__ Wr, const float* __restrict__ W1,
        const float* __restrict__ W2,
        __bf16* __restrict__ kb, __bf16* __restrict__ PEWb, __bf16* __restrict__ vTb,
        __bf16* __restrict__ WrB, __bf16* __restrict__ W1T, __bf16* __restrict__ W2T) {
    __shared__ __align__(16) float s_row[H_];
    int t = threadIdx.x;
    if (blockIdx.x < SEG_KV) {
        int p = blockIdx.x;
        {
            int j = (t < 64) ? t : (t - 64);
            double f = exp(-(double)j * (log(10000.0) / 63.0));
            double a = (double)p * f;
            s_row[t] = (float)((t < 64) ? sin(a) : cos(a));
        }
        __syncthreads();
        float acc0 = 0.f, acc1 = 0.f, acc2 = 0.f, acc3 = 0.f;
        for (int j = 0; j < H_; ++j) {
            float xv = s_row[j];
            int row = j * H_ + t;
            acc0 += xv * Wf[0 * H_ * H_ + row];
            acc1 += xv * Wf[1 * H_ * H_ + row];
            acc2 += xv * Wf[2 * H_ * H_ + row];
            acc3 += xv * Wf[3 * H_ * H_ + row];
        }
        PEWb[(0 * PEN_ + p) * H_ + t] = (__bf16)(acc0 + bfv[t]);  // bias folded
        PEWb[(1 * PEN_ + p) * H_ + t] = (__bf16)acc1;
        PEWb[(2 * PEN_ + p) * H_ + t] = (__bf16)acc2;
        PEWb[(3 * PEN_ + p) * H_ + t] = (__bf16)acc3;
    } else if (blockIdx.x < SEG_CVT) {
        int blk = blockIdx.x - SEG_KV;        // l*B*W + b*W + w
        int li = blk / (B_ * W_);
        int rem = blk % (B_ * W_);
        int bb = rem / W_, w = rem % W_;
        s_row[t] = words[rem * H_ + t];
        __syncthreads();
        const float4* row4 = (const float4*)s_row;
        const float* wk = Wk + li * H_ * H_;
        const float* wv = Wv + li * H_ * H_;
        float4 ak = {0,0,0,0}, av = {0,0,0,0};
        for (int g = 0; g < 32; ++g) {
            float4 x = row4[g];
            int j0 = 4 * g;
            ak.x += x.x * wk[(j0 + 0) * H_ + t];
            ak.y += x.y * wk[(j0 + 1) * H_ + t];
            ak.z += x.z * wk[(j0 + 2) * H_ + t];
            ak.w += x.w * wk[(j0 + 3) * H_ + t];
            av.x += x.x * wv[(j0 + 0) * H_ + t];
            av.y += x.y * wv[(j0 + 1) * H_ + t];
            av.z += x.z * wv[(j0 + 2) * H_ + t];
            av.w += x.w * wv[(j0 + 3) * H_ + t];
        }
        kb[(size_t)blk * H_ + t] = (__bf16)((ak.x + ak.y) + (ak.z + ak.w) + bk[li * H_ + t]);
        size_t vrow = ((size_t)(li * B_ + bb) * H_ + t) * WP_;
        vTb[vrow + w] = (__bf16)((av.x + av.y) + (av.z + av.w) + bv[li * H_ + t]);
        if (w == 0) {
            vTb[vrow + 300] = (__bf16)0.f; vTb[vrow + 301] = (__bf16)0.f;
            vTb[vrow + 302] = (__bf16)0.f; vTb[vrow + 303] = (__bf16)0.f;
        }
    } else {
        int blk2 = blockIdx.x - SEG_CVT;
        if (blk2 < N_WR_BLK) {                       // WrB: straight bf16 copy
            int i = blk2 * 128 + t;
            WrB[i] = (__bf16)Wr[i];
        } else if (blk2 < N_WR_BLK + N_W1_BLK) {     // W1T[l][u][j] = W1[l][j][u]
            int i = (blk2 - N_WR_BLK) * 128 + t;
            int j = i & 127; int rest = i >> 7; int u = rest & 511; int l = rest >> 9;
            W1T[i] = (__bf16)W1[(l * H_ + j) * FF_ + u];
        } else {                                      // W2T[l][h][u] = W2[l][u][h]
            int i = (blk2 - N_WR_BLK - N_W1_BLK) * 128 + t;
            int u = i & 511; int rest = i >> 9; int h = rest & 127; int l = rest >> 7;
            W2T[i] = (__bf16)W2[(l * FF_ + u) * H_ + h];
        }
    }
}

// ---------------- block-wide sum over first 128 lanes (blockDim >= 128)
__device__ __forceinline__ float block_sum_128(int t, float v, float* s_red) {
    __syncthreads();
    if (t < 128) s_red[t] = v;
    __syncthreads();
    if (t < 64) {
        float x = s_red[t] + s_red[t + 64];
        #pragma unroll
        for (int off = 32; off > 0; off >>= 1) x += __shfl_down(x, off);
        if (t == 0) s_red[0] = x;
    }
    __syncthreads();
    return s_red[0];
}

// ---------------- mega kernel: one block per (b,c), both layers; fp32 in/out
// 512 threads, (512,4) = 128-VGPR budget. R14 measured VGPR=56 -> headroom for
// wider in-flight load windows: score s-loop unroll 2, FF/qproj unroll 4.
__global__ __launch_bounds__(512, 4) void mega_kernel(
    const float* __restrict__ chars,
    const int* __restrict__ pos_s, const int* __restrict__ pos_e,
    const int* __restrict__ lex_s, const int* __restrict__ lex_e,
    const int* __restrict__ seq_len, const int* __restrict__ lex_num,
    const float* __restrict__ Wq, const float* __restrict__ bq,
    const float* __restrict__ br,
    const float* __restrict__ u_bias, const float* __restrict__ v_bias,
    const float* __restrict__ ln1_g, const float* __restrict__ ln1_b,
    const float* __restrict__ ln2_g, const float* __restrict__ ln2_b,
    const float* __restrict__ b1, const float* __restrict__ b2,
    const __bf16* __restrict__ kb, const __bf16* __restrict__ PEWb,
    const __bf16* __restrict__ vTb, const __bf16* __restrict__ WrB,
    const __bf16* __restrict__ W1T, const __bf16* __restrict__ W2T,
    float* __restrict__ out) {

    __shared__ __align__(16) float s_x[H_], s_qv[H_];
    __shared__ __align__(16) __bf16 s_wvecb[16][WVS_];   // rows 8..15 zero
    __shared__ __align__(16) __bf16 s_qub[16][WVS_];     // block-diag qu; off-diag zero
    __shared__ float s_bterm[NH_];
    __shared__ __align__(16) float s_sc[NH_][WP_];
    __shared__ float s_red[H_];
    __shared__ __align__(16) float s_hid[FF_];
    __shared__ float s_tmp[512];
    __shared__ int s_ls[W_], s_le[W_];

    int blk = blockIdx.x;
    int b = blk / C_, c = blk % C_;
    int t = threadIdx.x;              // 0..511
    int lane = t & 63;
    int wid = t >> 6;                 // 0..7
    int l15 = lane & 15, quad = lane >> 4;
    int h128 = t & 127, qtr = t >> 7; // 0..3

    if (t < H_) s_x[t] = chars[(b * C_ + c) * H_ + t];
    for (int w = t; w < W_; w += 512) {
        s_ls[w] = lex_s[b * W_ + w];
        s_le[w] = lex_e[b * W_ + w];
    }
    // zero init: wvecb rows 8..15 and ALL of qub (off-diagonal stays zero forever)
    for (int i = t; i < 8 * WVS_; i += 512)
        s_wvecb[8 + (i / WVS_)][i % WVS_] = (__bf16)0.f;
    for (int i = t; i < 16 * WVS_; i += 512)
        s_qub[i / WVS_][i % WVS_] = (__bf16)0.f;
    int ps = pos_s[b * C_ + c];
    int pev = pos_e[b * C_ + c];
    int cvalid = (c < seq_len[b]);
    int wnum = lex_num[b];
    __syncthreads();

    for (int li = 0; li < L_; ++li) {
        // ---- q projection: 512 threads, K split in quarters (fp32 weights)
        {
            const float* WqL = Wq + li * H_ * H_;
            const float4* x4 = (const float4*)s_x;
            float4 a4 = {0,0,0,0};
            #pragma unroll 4
            for (int g = qtr * 8; g < qtr * 8 + 8; ++g) {
                float4 x = x4[g];
                int j0 = 4 * g;
                a4.x += x.x * WqL[(j0 + 0) * H_ + h128];
                a4.y += x.y * WqL[(j0 + 1) * H_ + h128];
                a4.z += x.z * WqL[(j0 + 2) * H_ + h128];
                a4.w += x.w * WqL[(j0 + 3) * H_ + h128];
            }
            s_tmp[t] = (a4.x + a4.y) + (a4.z + a4.w);
        }
        __syncthreads();
        if (t < H_) {
            float acc = s_tmp[t] + s_tmp[t + 128] + s_tmp[t + 256] + s_tmp[t + 384]
                      + bq[li * H_ + t];
            s_qub[t >> 4][t] = (__bf16)(acc + u_bias[li * H_ + t]);  // block-diag B for A_C
            s_qv[t] = acc + v_bias[li * H_ + t];
        }
        __syncthreads();

        // ---- wvec: 1024 items (n,h), 2 per thread; bterm on last 8 threads
        {
            const __bf16* WrL = WrB + li * H_ * H_;
            #pragma unroll 2
            for (int it = 0; it < 2; ++it) {
                int item = t + it * 512;
                int n = item >> 7, h = item & 127;
                bf16x8 w0 = *(const bf16x8*)(WrL + h * H_ + n * PH_);
                bf16x8 w1 = *(const bf16x8*)(WrL + h * H_ + n * PH_ + 8);
                const float4* qv4 = (const float4*)(s_qv + n * PH_);
                float4 q0 = qv4[0], q1 = qv4[1], q2 = qv4[2], q3 = qv4[3];
                float4 a4;
                a4.x = (float)w0[0] * q0.x + (float)w1[0] * q2.x;
                a4.y = (float)w0[1] * q0.y + (float)w1[1] * q2.y;
                a4.z = (float)w0[2] * q0.z + (float)w1[2] * q2.z;
                a4.w = (float)w0[3] * q0.w + (float)w1[3] * q2.w;
                a4.x += (float)w0[4] * q1.x + (float)w1[4] * q3.x;
                a4.y += (float)w0[5] * q1.y + (float)w1[5] * q3.y;
                a4.z += (float)w0[6] * q1.z + (float)w1[6] * q3.z;
                a4.w += (float)w0[7] * q1.w + (float)w1[7] * q3.w;
                s_wvecb[n][h] = (__bf16)((a4.x + a4.y) + (a4.z + a4.w));
            }
            if (t >= 504) {
                int n = t - 504;
                const float4* br4 = (const float4*)(br + li * H_ + n * PH_);
                const float4* qv4 = (const float4*)(s_qv + n * PH_);
                float4 a4 = {0,0,0,0};
                #pragma unroll
                for (int i = 0; i < 4; ++i) {
                    float4 wv_ = br4[i], qv_ = qv4[i];
                    a4.x += wv_.x * qv_.x; a4.y += wv_.y * qv_.y;
                    a4.z += wv_.z * qv_.z; a4.w += wv_.w * qv_.w;
                }
                s_bterm[n] = (a4.x + a4.y) + (a4.z + a4.w);
            }
        }
        __syncthreads();

        // ---- score via MFMA: D[w,n] = rel·wvec (K=128) + k·qu_blockdiag (K=128)
        // unroll 2: ~10 bf16x8 global loads in flight — fits the 128-reg budget.
        const __bf16* kL = kb + (size_t)(li * B_ + b) * W_ * H_;
        const __bf16* wrow = &s_wvecb[l15][0];
        const __bf16* qrow = &s_qub[l15][0];
        for (int tile = wid; tile < (W_ + 15) / 16; tile += 8) {
            int w0 = tile * 16;
            int w = w0 + l15; if (w > W_ - 1) w = W_ - 1;
            int ls = s_ls[w], le = s_le[w];
            int i0 = min(max(ps - ls + MAXLEN_, 0), PEN_ - 1);
            int i1 = min(max(ps - le + MAXLEN_, 0), PEN_ - 1);
            int i2 = min(max(pev - ls + MAXLEN_, 0), PEN_ - 1);
            int i3 = min(max(pev - le + MAXLEN_, 0), PEN_ - 1);
            const __bf16* r0 = PEWb + (size_t)(0 * PEN_ + i0) * H_;
            const __bf16* r1 = PEWb + (size_t)(1 * PEN_ + i1) * H_;
            const __bf16* r2 = PEWb + (size_t)(2 * PEN_ + i2) * H_;
            const __bf16* r3 = PEWb + (size_t)(3 * PEN_ + i3) * H_;
            const __bf16* kr = kL + (size_t)w * H_;
            f32x4v acc = {0.f, 0.f, 0.f, 0.f};
            #pragma unroll 2
            for (int s = 0; s < 4; ++s) {
                int h0 = s * 32 + quad * 8;
                bf16x8 t0 = *(const bf16x8*)(r0 + h0);
                bf16x8 t1 = *(const bf16x8*)(r1 + h0);
                bf16x8 t2 = *(const bf16x8*)(r2 + h0);
                bf16x8 t3 = *(const bf16x8*)(r3 + h0);
                bf16x8 A;
                #pragma unroll
                for (int j = 0; j < 8; ++j)
                    A[j] = (__bf16)fmaxf((float)t0[j] + (float)t1[j] + (float)t2[j] + (float)t3[j], 0.f);
                bf16x8 Bf = *(const bf16x8*)(wrow + h0);   // LDS
                acc = __builtin_amdgcn_mfma_f32_16x16x32_bf16(A, Bf, acc, 0, 0, 0);
                bf16x8 K = *(const bf16x8*)(kr + h0);
                bf16x8 Bq = *(const bf16x8*)(qrow + h0);   // LDS
                acc = __builtin_amdgcn_mfma_f32_16x16x32_bf16(K, Bq, acc, 0, 0, 0);
            }
            if (l15 < NH_) {
                float bt = s_bterm[l15];
                #pragma unroll
                for (int r = 0; r < 4; ++r) {
                    int wr = w0 + quad * 4 + r;
                    if (wr < W_) s_sc[l15][wr] = acc[r] + bt;
                }
            }
        }
        __syncthreads();

        // ---- softmax per head (masked); 64 lanes per head; zero-fill pad to WP_
        {
            int n = t >> 6, ln_ = t & 63;
            if (cvalid) {
                float m = -INFINITY;
                for (int w = ln_; w < wnum; w += 64) m = fmaxf(m, s_sc[n][w]);
                #pragma unroll
                for (int off = 32; off > 0; off >>= 1) m = fmaxf(m, __shfl_xor(m, off, 64));
                float sum = 0.f;
                for (int w = ln_; w < wnum; w += 64) sum += expf(s_sc[n][w] - m);
                #pragma unroll
                for (int off = 32; off > 0; off >>= 1) sum += __shfl_xor(sum, off, 64);
                float inv = 1.f / sum;
                for (int w = ln_; w < WP_; w += 64)
                    s_sc[n][w] = (w < wnum) ? expf(s_sc[n][w] - m) * inv : 0.f;
            } else {
                for (int w = ln_; w < WP_; w += 64) s_sc[n][w] = 0.f;
            }
        }
        __syncthreads();

        // ---- ctx = att @ v; K (w-range) split in quarters; bf16 vT rows
        {
            int n = h128 >> 4;
            const __bf16* vrow = vTb + ((size_t)(li * B_ + b) * H_ + h128) * WP_;
            const float4* att4 = (const float4*)(s_sc[n]);
            float4 a4 = {0,0,0,0};
            int g0 = qtr * 10, g1 = g0 + 10 < 38 ? g0 + 10 : 38;
            #pragma unroll 2
            for (int g = g0; g < g1; ++g) {
                bf16x8 vv = *(const bf16x8*)(vrow + 8 * g);
                float4 p0 = att4[2 * g], p1 = att4[2 * g + 1];
                a4.x += p0.x * (float)vv[0] + p1.x * (float)vv[4];
                a4.y += p0.y * (float)vv[1] + p1.y * (float)vv[5];
                a4.z += p0.z * (float)vv[2] + p1.z * (float)vv[6];
                a4.w += p0.w * (float)vv[3] + p1.w * (float)vv[7];
            }
            s_tmp[t] = (a4.x + a4.y) + (a4.z + a4.w);
        }
        __syncthreads();

        // ---- LN1(ctx + x)
        float xln = 0.f;
        if (t < H_) xln = s_tmp[t] + s_tmp[t + 128] + s_tmp[t + 256] + s_tmp[t + 384] + s_x[t];
        float sum1 = block_sum_128(t, xln, s_red);
        float mean1 = sum1 * (1.f / 128.f);
        float d1 = xln - mean1;
        float vs1 = block_sum_128(t, (t < H_) ? d1 * d1 : 0.f, s_red);
        float rstd1 = rsqrtf(vs1 * (1.f / 128.f) + 1e-5f);
        if (t < H_)
            s_x[t] = d1 * rstd1 * ln1_g[li * H_ + t] + ln1_b[li * H_ + t];
        __syncthreads();

        // ---- FF hidden: one unit per thread; bf16 transposed rows
        {
            const __bf16* row = W1T + (size_t)li * FF_ * H_ + (size_t)t * H_;
            const float4* x4 = (const float4*)s_x;
            float4 a4 = {0,0,0,0};
            #pragma unroll 4
            for (int g = 0; g < 16; ++g) {
                bf16x8 wa = *(const bf16x8*)(row + 8 * g);
                float4 x0 = x4[2 * g], x1 = x4[2 * g + 1];
                a4.x += x0.x * (float)wa[0] + x1.x * (float)wa[4];
                a4.y += x0.y * (float)wa[1] + x1.y * (float)wa[5];
                a4.z += x0.z * (float)wa[2] + x1.z * (float)wa[6];
                a4.w += x0.w * (float)wa[3] + x1.w * (float)wa[7];
            }
            s_hid[t] = fmaxf((a4.x + a4.y) + (a4.z + a4.w) + b1[li * FF_ + t], 0.f);
        }
        __syncthreads();

        // ---- FF out: u-range split in quarters; bf16 transposed rows
        {
            const __bf16* wrow2 = W2T + ((size_t)li * H_ + h128) * FF_ + qtr * 128;
            const float4* h4 = (const float4*)(s_hid + qtr * 128);
            float4 a4 = {0,0,0,0};
            #pragma unroll 4
            for (int g = 0; g < 16; ++g) {
                bf16x8 wv = *(const bf16x8*)(wrow2 + 8 * g);
                float4 p0 = h4[2 * g], p1 = h4[2 * g + 1];
                a4.x += p0.x * (float)wv[0] + p1.x * (float)wv[4];
                a4.y += p0.y * (float)wv[1] + p1.y * (float)wv[5];
                a4.z += p0.z * (float)wv[2] + p1.z * (float)wv[6];
                a4.w += p0.w * (float)wv[3] + p1.w * (float)wv[7];
            }
            s_tmp[t] = (a4.x + a4.y) + (a4.z + a4.w);
        }
        __syncthreads();
        float x2 = 0.f;
        if (t < H_) x2 = s_tmp[t] + s_tmp[t + 128] + s_tmp[t + 256] + s_tmp[t + 384]
                       + b2[li * H_ + t] + s_x[t];
        float sum2 = block_sum_128(t, x2, s_red);
        float mean2 = sum2 * (1.f / 128.f);
        float d2 = x2 - mean2;
        float vs2 = block_sum_128(t, (t < H_) ? d2 * d2 : 0.f, s_red);
        float rstd2 = rsqrtf(vs2 * (1.f / 128.f) + 1e-5f);
        if (t < H_)
            s_x[t] = d2 * rstd2 * ln2_g[li * H_ + t] + ln2_b[li * H_ + t];
        __syncthreads();
    }

    if (t < H_) out[(b * C_ + c) * H_ + t] = s_x[t];
}

extern "C" void kernel_launch(void* const* d_in, const int* in_sizes, int n_in,
                              void* d_out, int out_size, void* d_ws, size_t ws_size,
                              hipStream_t stream) {
    const float* chars  = (const float*)d_in[0];
    const float* words  = (const float*)d_in[1];
    const int* pos_s   = (const int*)d_in[2];
    const int* pos_e   = (const int*)d_in[3];
    const int* lex_s   = (const int*)d_in[4];
    const int* lex_e   = (const int*)d_in[5];
    const int* seq_len = (const int*)d_in[6];
    const int* lex_num = (const int*)d_in[7];
    const float* Wf  = (const float*)d_in[8];
    const float* bfv = (const float*)d_in[9];
    const float* Wq  = (const float*)d_in[10];
    const float* bq  = (const float*)d_in[11];
    const float* Wk  = (const float*)d_in[12];
    const float* bk  = (const float*)d_in[13];
    const float* Wv  = (const float*)d_in[14];
    const float* bv  = (const float*)d_in[15];
    const float* Wr  = (const float*)d_in[16];
    const float* br  = (const float*)d_in[17];
    const float* u_bias = (const float*)d_in[18];
    const float* v_bias = (const float*)d_in[19];
    const float* ln1_g  = (const float*)d_in[20];
    const float* ln1_b  = (const float*)d_in[21];
    const float* ln2_g  = (const float*)d_in[22];
    const float* ln2_b  = (const float*)d_in[23];
    const float* W1  = (const float*)d_in[24];
    const float* b1  = (const float*)d_in[25];
    const float* W2  = (const float*)d_in[26];
    const float* b2  = (const float*)d_in[27];

    __bf16* kb   = (__bf16*)d_ws;                      // L*B*W*H  = 307200 bf16
    __bf16* PEWb = kb + (size_t)L_ * B_ * W_ * H_;     // 262144 bf16
    __bf16* vTb  = PEWb + 4 * PEN_ * H_;               // L*B*H*WP = 311296 bf16
    __bf16* WrB  = vTb + (size_t)L_ * B_ * H_ * WP_;   // 32768 bf16
    __bf16* W1T  = WrB + L_ * H_ * H_;                 // 131072 bf16
    __bf16* W2T  = W1T + L_ * H_ * FF_;                // 131072 bf16

    prep_kernel<<<dim3(PREP_BLOCKS), dim3(128), 0, stream>>>(
        Wf, bfv, words, Wk, bk, Wv, bv, Wr, W1, W2,
        kb, PEWb, vTb, WrB, W1T, W2T);

    mega_kernel<<<dim3(B_ * C_), dim3(512), 0, stream>>>(
        chars, pos_s, pos_e, lex_s, lex_e, seq_len, lex_num,
        Wq, bq, br, u_bias, v_bias,
        ln1_g, ln1_b, ln2_g, ln2_b, b1, b2,
        kb, PEWb, vTb, WrB, W1T, W2T, (float*)d_out);
}

// Round 16
// 308.109 us; speedup vs baseline: 1.1213x; 1.1213x over previous
//
#include <hip/hip_runtime.h>
#include <math.h>

#define B_ 4
#define C_ 200
#define W_ 300
#define WP_ 304          // padded W for bf16x8 rows
#define H_ 128
#define NH_ 8
#define PH_ 16
#define FF_ 512
#define L_ 2
#define MAXLEN_ 200
#define PEN_ 512
#define WVS_ 136         // LDS B-matrix row stride (bf16): 2-way-free banks, 16B aligned

typedef __bf16 bf16x8 __attribute__((ext_vector_type(8)));
typedef float f32x4v __attribute__((ext_vector_type(4)));

// prep grid segments
#define SEG_KV   (PEN_)                    // 512
#define SEG_CVT  (PEN_ + L_ * B_ * W_)     // 2912
#define N_WR_BLK   256                     // L*H*H/128
#define N_W1_BLK  1024                     // L*FF*H/128
#define N_W2_BLK  1024
#define PREP_BLOCKS (SEG_CVT + N_WR_BLK + N_W1_BLK + N_W2_BLK)   // 5216

// ---------------- prep: PEW(bf16, bias folded) | kb(bf16)/vT(bf16) | weight converts
__global__ __launch_bounds__(128) void prep_kernel(
        const float* __restrict__ Wf, const float* __restrict__ bfv,
        const float* __restrict__ words,
        const float* __restrict__ Wk, const float* __restrict__ bk,
        const float* __restrict__ Wv, const float* __restrict__ bv,
        const float* __restrict__ Wr, const float* __restrict__ W1,
        const float* __restrict__ W2,
        __bf16* __restrict__ kb, __bf16* __restrict__ PEWb, __bf16* __restrict__ vTb,
        __bf16* __restrict__ WrB, __bf16* __restrict__ W1T, __bf16* __restrict__ W2T) {
    __shared__ __align__(16) float s_row[H_];
    int t = threadIdx.x;
    if (blockIdx.x < SEG_KV) {
        int p = blockIdx.x;
        {
            int j = (t < 64) ? t : (t - 64);
            double f = exp(-(double)j * (log(10000.0) / 63.0));
            double a = (double)p * f;
            s_row[t] = (float)((t < 64) ? sin(a) : cos(a));
        }
        __syncthreads();
        float acc0 = 0.f, acc1 = 0.f, acc2 = 0.f, acc3 = 0.f;
        for (int j = 0; j < H_; ++j) {
            float xv = s_row[j];
            int row = j * H_ + t;
            acc0 += xv * Wf[0 * H_ * H_ + row];
            acc1 += xv * Wf[1 * H_ * H_ + row];
            acc2 += xv * Wf[2 * H_ * H_ + row];
            acc3 += xv * Wf[3 * H_ * H_ + row];
        }
        PEWb[(0 * PEN_ + p) * H_ + t] = (__bf16)(acc0 + bfv[t]);  // bias folded
        PEWb[(1 * PEN_ + p) * H_ + t] = (__bf16)acc1;
        PEWb[(2 * PEN_ + p) * H_ + t] = (__bf16)acc2;
        PEWb[(3 * PEN_ + p) * H_ + t] = (__bf16)acc3;
    } else if (blockIdx.x < SEG_CVT) {
        int blk = blockIdx.x - SEG_KV;        // l*B*W + b*W + w
        int li = blk / (B_ * W_);
        int rem = blk % (B_ * W_);
        int bb = rem / W_, w = rem % W_;
        s_row[t] = words[rem * H_ + t];
        __syncthreads();
        const float4* row4 = (const float4*)s_row;
        const float* wk = Wk + li * H_ * H_;
        const float* wv = Wv + li * H_ * H_;
        float4 ak = {0,0,0,0}, av = {0,0,0,0};
        for (int g = 0; g < 32; ++g) {
            float4 x = row4[g];
            int j0 = 4 * g;
            ak.x += x.x * wk[(j0 + 0) * H_ + t];
            ak.y += x.y * wk[(j0 + 1) * H_ + t];
            ak.z += x.z * wk[(j0 + 2) * H_ + t];
            ak.w += x.w * wk[(j0 + 3) * H_ + t];
            av.x += x.x * wv[(j0 + 0) * H_ + t];
            av.y += x.y * wv[(j0 + 1) * H_ + t];
            av.z += x.z * wv[(j0 + 2) * H_ + t];
            av.w += x.w * wv[(j0 + 3) * H_ + t];
        }
        kb[(size_t)blk * H_ + t] = (__bf16)((ak.x + ak.y) + (ak.z + ak.w) + bk[li * H_ + t]);
        size_t vrow = ((size_t)(li * B_ + bb) * H_ + t) * WP_;
        vTb[vrow + w] = (__bf16)((av.x + av.y) + (av.z + av.w) + bv[li * H_ + t]);
        if (w == 0) {
            vTb[vrow + 300] = (__bf16)0.f; vTb[vrow + 301] = (__bf16)0.f;
            vTb[vrow + 302] = (__bf16)0.f; vTb[vrow + 303] = (__bf16)0.f;
        }
    } else {
        int blk2 = blockIdx.x - SEG_CVT;
        if (blk2 < N_WR_BLK) {                       // WrB: straight bf16 copy
            int i = blk2 * 128 + t;
            WrB[i] = (__bf16)Wr[i];
        } else if (blk2 < N_WR_BLK + N_W1_BLK) {     // W1T[l][u][j] = W1[l][j][u]
            int i = (blk2 - N_WR_BLK) * 128 + t;
            int j = i & 127; int rest = i >> 7; int u = rest & 511; int l = rest >> 9;
            W1T[i] = (__bf16)W1[(l * H_ + j) * FF_ + u];
        } else {                                      // W2T[l][h][u] = W2[l][u][h]
            int i = (blk2 - N_WR_BLK - N_W1_BLK) * 128 + t;
            int u = i & 511; int rest = i >> 9; int h = rest & 127; int l = rest >> 7;
            W2T[i] = (__bf16)W2[(l * FF_ + u) * H_ + h];
        }
    }
}

// ---------------- fused LayerNorm over 128 values in s_red[0..127]:
// wave 0 computes sum & sumsq in ONE shuffle pass (var = E[x^2]-mean^2),
// stores mean/rstd at s_red[128..129]. 3 barriers total vs 7 for tree-sums.
__device__ __forceinline__ void ln_reduce_128(int t, float* s_red) {
    __syncthreads();                 // s_red[0..127] visible
    if (t < 64) {
        float a = s_red[t], b = s_red[t + 64];
        float s = a + b, ss = a * a + b * b;
        #pragma unroll
        for (int off = 32; off > 0; off >>= 1) {
            s += __shfl_down(s, off);
            ss += __shfl_down(ss, off);
        }
        if (t == 0) {
            float mean = s * (1.f / 128.f);
            float var = ss * (1.f / 128.f) - mean * mean;
            s_red[128] = mean;
            s_red[129] = rsqrtf(var + 1e-5f);
        }
    }
    __syncthreads();                 // mean/rstd visible
}

// ---------------- mega kernel: one block per (b,c), both layers; fp32 in/out
// R13 structure (256 thr, (256,4)=64-VGPR spill-free, unroll 1/2 throttles) +
// fused single-pass LNs: barriers/layer 22 -> 14 (LN was 7 barriers, now 3).
__global__ __launch_bounds__(256, 4) void mega_kernel(
    const float* __restrict__ chars,
    const int* __restrict__ pos_s, const int* __restrict__ pos_e,
    const int* __restrict__ lex_s, const int* __restrict__ lex_e,
    const int* __restrict__ seq_len, const int* __restrict__ lex_num,
    const float* __restrict__ Wq, const float* __restrict__ bq,
    const float* __restrict__ br,
    const float* __restrict__ u_bias, const float* __restrict__ v_bias,
    const float* __restrict__ ln1_g, const float* __restrict__ ln1_b,
    const float* __restrict__ ln2_g, const float* __restrict__ ln2_b,
    const float* __restrict__ b1, const float* __restrict__ b2,
    const __bf16* __restrict__ kb, const __bf16* __restrict__ PEWb,
    const __bf16* __restrict__ vTb, const __bf16* __restrict__ WrB,
    const __bf16* __restrict__ W1T, const __bf16* __restrict__ W2T,
    float* __restrict__ out) {

    __shared__ __align__(16) float s_x[H_], s_qv[H_];
    __shared__ __align__(16) __bf16 s_wvecb[16][WVS_];   // rows 8..15 zero
    __shared__ __align__(16) __bf16 s_qub[16][WVS_];     // block-diag qu; off-diag zero
    __shared__ float s_bterm[NH_];
    __shared__ __align__(16) float s_sc[NH_][WP_];
    __shared__ float s_red[132];                          // [0..127] vals, [128..129] mean/rstd
    __shared__ __align__(16) float s_hid[FF_];
    __shared__ float s_tmp[256];
    __shared__ int s_ls[W_], s_le[W_];

    int blk = blockIdx.x;
    int b = blk / C_, c = blk % C_;
    int t = threadIdx.x;
    int lane = t & 63;
    int wid = t >> 6;
    int l15 = lane & 15, quad = lane >> 4;

    if (t < H_) s_x[t] = chars[(b * C_ + c) * H_ + t];
    for (int w = t; w < W_; w += 256) {
        s_ls[w] = lex_s[b * W_ + w];
        s_le[w] = lex_e[b * W_ + w];
    }
    // zero init: wvecb rows 8..15 and ALL of qub (off-diagonal stays zero forever)
    for (int i = t; i < 8 * WVS_; i += 256)
        s_wvecb[8 + (i / WVS_)][i % WVS_] = (__bf16)0.f;
    for (int i = t; i < 16 * WVS_; i += 256)
        s_qub[i / WVS_][i % WVS_] = (__bf16)0.f;
    int ps = pos_s[b * C_ + c];
    int pev = pos_e[b * C_ + c];
    int cvalid = (c < seq_len[b]);
    int wnum = lex_num[b];
    __syncthreads();

    for (int li = 0; li < L_; ++li) {
        // ---- q projection: all 256 threads, K split in halves (fp32 weights)
        {
            int half = t >> 7, h = t & 127;
            const float* WqL = Wq + li * H_ * H_;
            const float4* x4 = (const float4*)s_x;
            float4 a4 = {0,0,0,0};
            #pragma unroll 2
            for (int g = half * 16; g < half * 16 + 16; ++g) {
                float4 x = x4[g];
                int j0 = 4 * g;
                a4.x += x.x * WqL[(j0 + 0) * H_ + h];
                a4.y += x.y * WqL[(j0 + 1) * H_ + h];
                a4.z += x.z * WqL[(j0 + 2) * H_ + h];
                a4.w += x.w * WqL[(j0 + 3) * H_ + h];
            }
            s_tmp[t] = (a4.x + a4.y) + (a4.z + a4.w);
        }
        __syncthreads();
        if (t < H_) {
            float acc = s_tmp[t] + s_tmp[t + 128] + bq[li * H_ + t];
            s_qub[t >> 4][t] = (__bf16)(acc + u_bias[li * H_ + t]);  // block-diag B for A_C
            s_qv[t] = acc + v_bias[li * H_ + t];
        }
        __syncthreads();

        // ---- wvec[n][h] -> bf16 LDS (B-fragment source); bterm[n] = br[n*16..]·qv
        if (t < H_) {
            const __bf16* WrRow = WrB + li * H_ * H_ + t * H_;
            #pragma unroll 2
            for (int n = 0; n < NH_; ++n) {
                bf16x8 w0 = *(const bf16x8*)(WrRow + n * PH_);
                bf16x8 w1 = *(const bf16x8*)(WrRow + n * PH_ + 8);
                const float4* qv4 = (const float4*)(s_qv + n * PH_);
                float4 q0 = qv4[0], q1 = qv4[1], q2 = qv4[2], q3 = qv4[3];
                float4 a4;
                a4.x = (float)w0[0] * q0.x + (float)w1[0] * q2.x;
                a4.y = (float)w0[1] * q0.y + (float)w1[1] * q2.y;
                a4.z = (float)w0[2] * q0.z + (float)w1[2] * q2.z;
                a4.w = (float)w0[3] * q0.w + (float)w1[3] * q2.w;
                a4.x += (float)w0[4] * q1.x + (float)w1[4] * q3.x;
                a4.y += (float)w0[5] * q1.y + (float)w1[5] * q3.y;
                a4.z += (float)w0[6] * q1.z + (float)w1[6] * q3.z;
                a4.w += (float)w0[7] * q1.w + (float)w1[7] * q3.w;
                s_wvecb[n][t] = (__bf16)((a4.x + a4.y) + (a4.z + a4.w));
            }
        } else if (t < H_ + NH_) {
            int n = t - H_;
            const float4* br4 = (const float4*)(br + li * H_ + n * PH_);
            const float4* qv4 = (const float4*)(s_qv + n * PH_);
            float4 a4 = {0,0,0,0};
            #pragma unroll
            for (int i = 0; i < 4; ++i) {
                float4 wv_ = br4[i], qv_ = qv4[i];
                a4.x += wv_.x * qv_.x; a4.y += wv_.y * qv_.y;
                a4.z += wv_.z * qv_.z; a4.w += wv_.w * qv_.w;
            }
            s_bterm[n] = (a4.x + a4.y) + (a4.z + a4.w);
        }
        __syncthreads();

        // ---- score via MFMA: D[w,n] = rel·wvec (K=128) + k·qu_blockdiag (K=128)
        // unroll 1: only 4 global bf16x8 loads in flight -> fits 64-reg budget.
        const __bf16* kL = kb + (size_t)(li * B_ + b) * W_ * H_;
        const __bf16* wrow = &s_wvecb[l15][0];
        const __bf16* qrow = &s_qub[l15][0];
        for (int tile = wid; tile < (W_ + 15) / 16; tile += 4) {
            int w0 = tile * 16;
            int w = w0 + l15; if (w > W_ - 1) w = W_ - 1;
            int ls = s_ls[w], le = s_le[w];
            int i0 = min(max(ps - ls + MAXLEN_, 0), PEN_ - 1);
            int i1 = min(max(ps - le + MAXLEN_, 0), PEN_ - 1);
            int i2 = min(max(pev - ls + MAXLEN_, 0), PEN_ - 1);
            int i3 = min(max(pev - le + MAXLEN_, 0), PEN_ - 1);
            const __bf16* r0 = PEWb + (size_t)(0 * PEN_ + i0) * H_;
            const __bf16* r1 = PEWb + (size_t)(1 * PEN_ + i1) * H_;
            const __bf16* r2 = PEWb + (size_t)(2 * PEN_ + i2) * H_;
            const __bf16* r3 = PEWb + (size_t)(3 * PEN_ + i3) * H_;
            const __bf16* kr = kL + (size_t)w * H_;
            f32x4v acc = {0.f, 0.f, 0.f, 0.f};
            #pragma unroll 1
            for (int s = 0; s < 4; ++s) {
                int h0 = s * 32 + quad * 8;
                bf16x8 t0 = *(const bf16x8*)(r0 + h0);
                bf16x8 t1 = *(const bf16x8*)(r1 + h0);
                bf16x8 t2 = *(const bf16x8*)(r2 + h0);
                bf16x8 t3 = *(const bf16x8*)(r3 + h0);
                bf16x8 A;
                #pragma unroll
                for (int j = 0; j < 8; ++j)
                    A[j] = (__bf16)fmaxf((float)t0[j] + (float)t1[j] + (float)t2[j] + (float)t3[j], 0.f);
                bf16x8 Bf = *(const bf16x8*)(wrow + h0);   // LDS
                acc = __builtin_amdgcn_mfma_f32_16x16x32_bf16(A, Bf, acc, 0, 0, 0);
                bf16x8 K = *(const bf16x8*)(kr + h0);
                bf16x8 Bq = *(const bf16x8*)(qrow + h0);   // LDS
                acc = __builtin_amdgcn_mfma_f32_16x16x32_bf16(K, Bq, acc, 0, 0, 0);
            }
            if (l15 < NH_) {
                float bt = s_bterm[l15];
                #pragma unroll
                for (int r = 0; r < 4; ++r) {
                    int wr = w0 + quad * 4 + r;
                    if (wr < W_) s_sc[l15][wr] = acc[r] + bt;
                }
            }
        }
        __syncthreads();

        // ---- softmax per head (masked); zero-fill pad to WP_
        {
            int n = t >> 5, ln_ = t & 31;
            if (cvalid) {
                float m = -INFINITY;
                for (int w = ln_; w < wnum; w += 32) m = fmaxf(m, s_sc[n][w]);
                #pragma unroll
                for (int off = 16; off > 0; off >>= 1) m = fmaxf(m, __shfl_xor(m, off, 32));
                float sum = 0.f;
                for (int w = ln_; w < wnum; w += 32) sum += expf(s_sc[n][w] - m);
                #pragma unroll
                for (int off = 16; off > 0; off >>= 1) sum += __shfl_xor(sum, off, 32);
                float inv = 1.f / sum;
                for (int w = ln_; w < WP_; w += 32)
                    s_sc[n][w] = (w < wnum) ? expf(s_sc[n][w] - m) * inv : 0.f;
            } else {
                for (int w = ln_; w < WP_; w += 32) s_sc[n][w] = 0.f;
            }
        }
        __syncthreads();

        // ---- ctx = att @ v via transposed bf16 v rows
        {
            int h = t & 127, half = t >> 7, n = h >> 4;
            const __bf16* vrow = vTb + ((size_t)(li * B_ + b) * H_ + h) * WP_;
            const float4* att4 = (const float4*)(s_sc[n]);
            float4 a4 = {0,0,0,0};
            #pragma unroll 2
            for (int g = half * 19; g < half * 19 + 19; ++g) {
                bf16x8 vv = *(const bf16x8*)(vrow + 8 * g);
                float4 p0 = att4[2 * g], p1 = att4[2 * g + 1];
                a4.x += p0.x * (float)vv[0] + p1.x * (float)vv[4];
                a4.y += p0.y * (float)vv[1] + p1.y * (float)vv[5];
                a4.z += p0.z * (float)vv[2] + p1.z * (float)vv[6];
                a4.w += p0.w * (float)vv[3] + p1.w * (float)vv[7];
            }
            s_tmp[t] = (a4.x + a4.y) + (a4.z + a4.w);
        }
        __syncthreads();

        // ---- LN1(ctx + x): fused single-pass reduction (3 barriers)
        if (t < H_) s_red[t] = s_tmp[t] + s_tmp[t + 128] + s_x[t];
        ln_reduce_128(t, s_red);
        if (t < H_)
            s_x[t] = (s_red[t] - s_red[128]) * s_red[129] * ln1_g[li * H_ + t]
                   + ln1_b[li * H_ + t];
        __syncthreads();

        // ---- FF hidden: thread t -> units (2t, 2t+1); bf16 transposed rows
        {
            const __bf16* W1l = W1T + (size_t)li * FF_ * H_;
            int u0 = t * 2;
            const __bf16* ra = W1l + (size_t)u0 * H_;
            const __bf16* rb = W1l + (size_t)(u0 + 1) * H_;
            const float4* x4 = (const float4*)s_x;
            float4 a04 = {0,0,0,0}, a14 = {0,0,0,0};
            #pragma unroll 2
            for (int g = 0; g < 16; ++g) {
                bf16x8 wa = *(const bf16x8*)(ra + 8 * g);
                bf16x8 wb = *(const bf16x8*)(rb + 8 * g);
                float4 x0 = x4[2 * g], x1 = x4[2 * g + 1];
                a04.x += x0.x * (float)wa[0] + x1.x * (float)wa[4];
                a04.y += x0.y * (float)wa[1] + x1.y * (float)wa[5];
                a04.z += x0.z * (float)wa[2] + x1.z * (float)wa[6];
                a04.w += x0.w * (float)wa[3] + x1.w * (float)wa[7];
                a14.x += x0.x * (float)wb[0] + x1.x * (float)wb[4];
                a14.y += x0.y * (float)wb[1] + x1.y * (float)wb[5];
                a14.z += x0.z * (float)wb[2] + x1.z * (float)wb[6];
                a14.w += x0.w * (float)wb[3] + x1.w * (float)wb[7];
            }
            float a0 = (a04.x + a04.y) + (a04.z + a04.w) + b1[li * FF_ + u0];
            float a1 = (a14.x + a14.y) + (a14.z + a14.w) + b1[li * FF_ + u0 + 1];
            s_hid[u0] = fmaxf(a0, 0.f);
            s_hid[u0 + 1] = fmaxf(a1, 0.f);
        }
        __syncthreads();

        // ---- FF out: 256 threads, u-range split in halves; bf16 transposed rows
        {
            int half = t >> 7, h = t & 127;
            const __bf16* wrow2 = W2T + ((size_t)li * H_ + h) * FF_ + half * 256;
            const float4* h4 = (const float4*)(s_hid + half * 256);
            float4 a4 = {0,0,0,0};
            #pragma unroll 2
            for (int g = 0; g < 32; ++g) {
                bf16x8 wv = *(const bf16x8*)(wrow2 + 8 * g);
                float4 p0 = h4[2 * g], p1 = h4[2 * g + 1];
                a4.x += p0.x * (float)wv[0] + p1.x * (float)wv[4];
                a4.y += p0.y * (float)wv[1] + p1.y * (float)wv[5];
                a4.z += p0.z * (float)wv[2] + p1.z * (float)wv[6];
                a4.w += p0.w * (float)wv[3] + p1.w * (float)wv[7];
            }
            s_tmp[t] = (a4.x + a4.y) + (a4.z + a4.w);
        }
        __syncthreads();

        // ---- LN2(ff + x): fused single-pass reduction (3 barriers)
        if (t < H_)
            s_red[t] = s_tmp[t] + s_tmp[t + 128] + b2[li * H_ + t] + s_x[t];
        ln_reduce_128(t, s_red);
        if (t < H_)
            s_x[t] = (s_red[t] - s_red[128]) * s_red[129] * ln2_g[li * H_ + t]
                   + ln2_b[li * H_ + t];
        __syncthreads();
    }

    if (t < H_) out[(b * C_ + c) * H_ + t] = s_x[t];
}

extern "C" void kernel_launch(void* const* d_in, const int* in_sizes, int n_in,
                              void* d_out, int out_size, void* d_ws, size_t ws_size,
                              hipStream_t stream) {
    const float* chars  = (const float*)d_in[0];
    const float* words  = (const float*)d_in[1];
    const int* pos_s   = (const int*)d_in[2];
    const int* pos_e   = (const int*)d_in[3];
    const int* lex_s   = (const int*)d_in[4];
    const int* lex_e   = (const int*)d_in[5];
    const int* seq_len = (const int*)d_in[6];
    const int* lex_num = (const int*)d_in[7];
    const float* Wf  = (const float*)d_in[8];
    const float* bfv = (const float*)d_in[9];
    const float* Wq  = (const float*)d_in[10];
    const float* bq  = (const float*)d_in[11];
    const float* Wk  = (const float*)d_in[12];
    const float* bk  = (const float*)d_in[13];
    const float* Wv  = (const float*)d_in[14];
    const float* bv  = (const float*)d_in[15];
    const float* Wr  = (const float*)d_in[16];
    const float* br  = (const float*)d_in[17];
    const float* u_bias = (const float*)d_in[18];
    const float* v_bias = (const float*)d_in[19];
    const float* ln1_g  = (const float*)d_in[20];
    const float* ln1_b  = (const float*)d_in[21];
    const float* ln2_g  = (const float*)d_in[22];
    const float* ln2_b  = (const float*)d_in[23];
    const float* W1  = (const float*)d_in[24];
    const float* b1  = (const float*)d_in[25];
    const float* W2  = (const float*)d_in[26];
    const float* b2  = (const float*)d_in[27];

    __bf16* kb   = (__bf16*)d_ws;                      // L*B*W*H  = 307200 bf16
    __bf16* PEWb = kb + (size_t)L_ * B_ * W_ * H_;     // 262144 bf16
    __bf16* vTb  = PEWb + 4 * PEN_ * H_;               // L*B*H*WP = 311296 bf16
    __bf16* WrB  = vTb + (size_t)L_ * B_ * H_ * WP_;   // 32768 bf16
    __bf16* W1T  = WrB + L_ * H_ * H_;                 // 131072 bf16
    __bf16* W2T  = W1T + L_ * H_ * FF_;                // 131072 bf16

    prep_kernel<<<dim3(PREP_BLOCKS), dim3(128), 0, stream>>>(
        Wf, bfv, words, Wk, bk, Wv, bv, Wr, W1, W2,
        kb, PEWb, vTb, WrB, W1T, W2T);

    mega_kernel<<<dim3(B_ * C_), dim3(256), 0, stream>>>(
        chars, pos_s, pos_e, lex_s, lex_e, seq_len, lex_num,
        Wq, bq, br, u_bias, v_bias,
        ln1_g, ln1_b, ln2_g, ln2_b, b1, b2,
        kb, PEWb, vTb, WrB, W1T, W2T, (float*)d_out);
}

// Round 18
// 270.250 us; speedup vs baseline: 1.2783x; 1.1401x over previous
//
#include <hip/hip_runtime.h>
#include <math.h>

#define B_ 4
#define C_ 200
#define CH_ 100          // rows per batch half; block r-pair = (c0, c0+100)
#define W_ 300
#define WP_ 304
#define H_ 128
#define NH_ 8
#define PH_ 16
#define FF_ 512
#define L_ 2
#define MAXLEN_ 200
#define PEN_ 512
#define WVS_ 136         // LDS B-matrix row stride (bf16)

typedef __bf16 bf16x8 __attribute__((ext_vector_type(8)));
typedef float f32x4v __attribute__((ext_vector_type(4)));

// prep grid segments
#define SEG_KV   (PEN_)
#define SEG_CVT  (PEN_ + L_ * B_ * W_)
#define N_WR_BLK   256
#define N_W1_BLK  1024
#define N_W2_BLK  1024
#define PREP_BLOCKS (SEG_CVT + N_WR_BLK + N_W1_BLK + N_W2_BLK)

// ---------------- prep (identical to R13/R16 proven version)
__global__ __launch_bounds__(128) void prep_kernel(
        const float* __restrict__ Wf, const float* __restrict__ bfv,
        const float* __restrict__ words,
        const float* __restrict__ Wk, const float* __restrict__ bk,
        const float* __restrict__ Wv, const float* __restrict__ bv,
        const float* __restrict__ Wr, const float* __restrict__ W1,
        const float* __restrict__ W2,
        __bf16* __restrict__ kb, __bf16* __restrict__ PEWb, __bf16* __restrict__ vTb,
        __bf16* __restrict__ WrB, __bf16* __restrict__ W1T, __bf16* __restrict__ W2T) {
    __shared__ __align__(16) float s_row[H_];
    int t = threadIdx.x;
    if (blockIdx.x < SEG_KV) {
        int p = blockIdx.x;
        {
            int j = (t < 64) ? t : (t - 64);
            double f = exp(-(double)j * (log(10000.0) / 63.0));
            double a = (double)p * f;
            s_row[t] = (float)((t < 64) ? sin(a) : cos(a));
        }
        __syncthreads();
        float acc0 = 0.f, acc1 = 0.f, acc2 = 0.f, acc3 = 0.f;
        for (int j = 0; j < H_; ++j) {
            float xv = s_row[j];
            int row = j * H_ + t;
            acc0 += xv * Wf[0 * H_ * H_ + row];
            acc1 += xv * Wf[1 * H_ * H_ + row];
            acc2 += xv * Wf[2 * H_ * H_ + row];
            acc3 += xv * Wf[3 * H_ * H_ + row];
        }
        PEWb[(0 * PEN_ + p) * H_ + t] = (__bf16)(acc0 + bfv[t]);
        PEWb[(1 * PEN_ + p) * H_ + t] = (__bf16)acc1;
        PEWb[(2 * PEN_ + p) * H_ + t] = (__bf16)acc2;
        PEWb[(3 * PEN_ + p) * H_ + t] = (__bf16)acc3;
    } else if (blockIdx.x < SEG_CVT) {
        int blk = blockIdx.x - SEG_KV;
        int li = blk / (B_ * W_);
        int rem = blk % (B_ * W_);
        int bb = rem / W_, w = rem % W_;
        s_row[t] = words[rem * H_ + t];
        __syncthreads();
        const float4* row4 = (const float4*)s_row;
        const float* wk = Wk + li * H_ * H_;
        const float* wv = Wv + li * H_ * H_;
        float4 ak = {0,0,0,0}, av = {0,0,0,0};
        for (int g = 0; g < 32; ++g) {
            float4 x = row4[g];
            int j0 = 4 * g;
            ak.x += x.x * wk[(j0 + 0) * H_ + t];
            ak.y += x.y * wk[(j0 + 1) * H_ + t];
            ak.z += x.z * wk[(j0 + 2) * H_ + t];
            ak.w += x.w * wk[(j0 + 3) * H_ + t];
            av.x += x.x * wv[(j0 + 0) * H_ + t];
            av.y += x.y * wv[(j0 + 1) * H_ + t];
            av.z += x.z * wv[(j0 + 2) * H_ + t];
            av.w += x.w * wv[(j0 + 3) * H_ + t];
        }
        kb[(size_t)blk * H_ + t] = (__bf16)((ak.x + ak.y) + (ak.z + ak.w) + bk[li * H_ + t]);
        size_t vrow = ((size_t)(li * B_ + bb) * H_ + t) * WP_;
        vTb[vrow + w] = (__bf16)((av.x + av.y) + (av.z + av.w) + bv[li * H_ + t]);
        if (w == 0) {
            vTb[vrow + 300] = (__bf16)0.f; vTb[vrow + 301] = (__bf16)0.f;
            vTb[vrow + 302] = (__bf16)0.f; vTb[vrow + 303] = (__bf16)0.f;
        }
    } else {
        int blk2 = blockIdx.x - SEG_CVT;
        if (blk2 < N_WR_BLK) {
            int i = blk2 * 128 + t;
            WrB[i] = (__bf16)Wr[i];
        } else if (blk2 < N_WR_BLK + N_W1_BLK) {
            int i = (blk2 - N_WR_BLK) * 128 + t;
            int j = i & 127; int rest = i >> 7; int u = rest & 511; int l = rest >> 9;
            W1T[i] = (__bf16)W1[(l * H_ + j) * FF_ + u];
        } else {
            int i = (blk2 - N_WR_BLK - N_W1_BLK) * 128 + t;
            int u = i & 511; int rest = i >> 9; int h = rest & 127; int l = rest >> 7;
            W2T[i] = (__bf16)W2[(l * FF_ + u) * H_ + h];
        }
    }
}

// ---------------- mega: one block per TWO rows (b,c0) and (b,c0+100); fp32 in/out
// Same-b pairing amortizes every weight/k/v load x2 and halves barriers per row.
// (256,2): ~2 blocks/CU resident (grid 400) -> large VGPR budget, no spill.
__global__ __launch_bounds__(256, 2) void mega_kernel(
    const float* __restrict__ chars,
    const int* __restrict__ pos_s, const int* __restrict__ pos_e,
    const int* __restrict__ lex_s, const int* __restrict__ lex_e,
    const int* __restrict__ seq_len, const int* __restrict__ lex_num,
    const float* __restrict__ Wq, const float* __restrict__ bq,
    const float* __restrict__ br,
    const float* __restrict__ u_bias, const float* __restrict__ v_bias,
    const float* __restrict__ ln1_g, const float* __restrict__ ln1_b,
    const float* __restrict__ ln2_g, const float* __restrict__ ln2_b,
    const float* __restrict__ b1, const float* __restrict__ b2,
    const __bf16* __restrict__ kb, const __bf16* __restrict__ PEWb,
    const __bf16* __restrict__ vTb, const __bf16* __restrict__ WrB,
    const __bf16* __restrict__ W1T, const __bf16* __restrict__ W2T,
    float* __restrict__ out) {

    __shared__ __align__(16) float s_x[2][H_], s_qv[2][H_];
    __shared__ __align__(16) __bf16 s_wvecb[2][16][WVS_];
    __shared__ __align__(16) __bf16 s_qub[2][16][WVS_];
    __shared__ float s_bterm[2][NH_];
    __shared__ __align__(16) float s_sc[2][NH_][WP_];
    __shared__ float s_red[2][132];
    __shared__ __align__(16) float s_hid[2][FF_];
    __shared__ float s_tmp[2][256];
    __shared__ int s_ls[W_], s_le[W_];

    int blk = blockIdx.x;               // 0..399
    int b = blk / CH_, c0 = blk % CH_;  // rows: c0, c0+100 (same b)
    int t = threadIdx.x;
    int lane = t & 63;
    int wid = t >> 6;
    int l15 = lane & 15, quad = lane >> 4;

    if (t < H_) {
        s_x[0][t] = chars[(b * C_ + c0) * H_ + t];
        s_x[1][t] = chars[(b * C_ + c0 + CH_) * H_ + t];
    }
    for (int w = t; w < W_; w += 256) {
        s_ls[w] = lex_s[b * W_ + w];
        s_le[w] = lex_e[b * W_ + w];
    }
    for (int i = t; i < 2 * 8 * WVS_; i += 256) {
        int r = i / (8 * WVS_), rem = i % (8 * WVS_);
        s_wvecb[r][8 + rem / WVS_][rem % WVS_] = (__bf16)0.f;
    }
    for (int i = t; i < 2 * 16 * WVS_; i += 256) {
        int r = i / (16 * WVS_), rem = i % (16 * WVS_);
        s_qub[r][rem / WVS_][rem % WVS_] = (__bf16)0.f;
    }
    int ps0 = pos_s[b * C_ + c0],        pev0 = pos_e[b * C_ + c0];
    int ps1 = pos_s[b * C_ + c0 + CH_],  pev1 = pos_e[b * C_ + c0 + CH_];
    int slen = seq_len[b];
    int cvalid0 = (c0 < slen), cvalid1 = (c0 + CH_ < slen);
    int wnum = lex_num[b];
    __syncthreads();

    for (int li = 0; li < L_; ++li) {
        // ---- q projection: weights loaded once, used for both rows
        {
            int half = t >> 7, h = t & 127;
            const float* WqL = Wq + li * H_ * H_;
            const float4* x40 = (const float4*)s_x[0];
            const float4* x41 = (const float4*)s_x[1];
            float4 a0 = {0,0,0,0}, a1 = {0,0,0,0};
            #pragma unroll 2
            for (int g = half * 16; g < half * 16 + 16; ++g) {
                float4 xa = x40[g], xb = x41[g];
                int j0 = 4 * g;
                float w0 = WqL[(j0 + 0) * H_ + h], w1 = WqL[(j0 + 1) * H_ + h];
                float w2 = WqL[(j0 + 2) * H_ + h], w3 = WqL[(j0 + 3) * H_ + h];
                a0.x += xa.x * w0; a0.y += xa.y * w1; a0.z += xa.z * w2; a0.w += xa.w * w3;
                a1.x += xb.x * w0; a1.y += xb.y * w1; a1.z += xb.z * w2; a1.w += xb.w * w3;
            }
            s_tmp[0][t] = (a0.x + a0.y) + (a0.z + a0.w);
            s_tmp[1][t] = (a1.x + a1.y) + (a1.z + a1.w);
        }
        __syncthreads();
        if (t < H_) {
            #pragma unroll
            for (int r = 0; r < 2; ++r) {
                float acc = s_tmp[r][t] + s_tmp[r][t + 128] + bq[li * H_ + t];
                s_qub[r][t >> 4][t] = (__bf16)(acc + u_bias[li * H_ + t]);
                s_qv[r][t] = acc + v_bias[li * H_ + t];
            }
        }
        __syncthreads();

        // ---- wvec + bterm: Wr/br rows loaded once, two qv dots
        if (t < H_) {
            const __bf16* WrRow = WrB + li * H_ * H_ + t * H_;
            #pragma unroll 2
            for (int n = 0; n < NH_; ++n) {
                bf16x8 w0 = *(const bf16x8*)(WrRow + n * PH_);
                bf16x8 w1 = *(const bf16x8*)(WrRow + n * PH_ + 8);
                #pragma unroll
                for (int r = 0; r < 2; ++r) {
                    const float4* qv4 = (const float4*)(s_qv[r] + n * PH_);
                    float4 q0 = qv4[0], q1 = qv4[1], q2 = qv4[2], q3 = qv4[3];
                    float4 a4;
                    a4.x = (float)w0[0] * q0.x + (float)w1[0] * q2.x;
                    a4.y = (float)w0[1] * q0.y + (float)w1[1] * q2.y;
                    a4.z = (float)w0[2] * q0.z + (float)w1[2] * q2.z;
                    a4.w = (float)w0[3] * q0.w + (float)w1[3] * q2.w;
                    a4.x += (float)w0[4] * q1.x + (float)w1[4] * q3.x;
                    a4.y += (float)w0[5] * q1.y + (float)w1[5] * q3.y;
                    a4.z += (float)w0[6] * q1.z + (float)w1[6] * q3.z;
                    a4.w += (float)w0[7] * q1.w + (float)w1[7] * q3.w;
                    s_wvecb[r][n][t] = (__bf16)((a4.x + a4.y) + (a4.z + a4.w));
                }
            }
        } else if (t < H_ + NH_) {
            int n = t - H_;
            const float4* br4 = (const float4*)(br + li * H_ + n * PH_);
            float4 b0 = br4[0], b1v = br4[1], b2v = br4[2], b3v = br4[3];
            #pragma unroll
            for (int r = 0; r < 2; ++r) {
                const float4* qv4 = (const float4*)(s_qv[r] + n * PH_);
                float4 q0 = qv4[0], q1 = qv4[1], q2 = qv4[2], q3 = qv4[3];
                float4 a4;
                a4.x = b0.x * q0.x + b2v.x * q2.x;
                a4.y = b0.y * q0.y + b2v.y * q2.y;
                a4.z = b0.z * q0.z + b2v.z * q2.z;
                a4.w = b0.w * q0.w + b2v.w * q2.w;
                a4.x += b1v.x * q1.x + b3v.x * q3.x;
                a4.y += b1v.y * q1.y + b3v.y * q3.y;
                a4.z += b1v.z * q1.z + b3v.z * q3.z;
                a4.w += b1v.w * q1.w + b3v.w * q3.w;
                s_bterm[r][n] = (a4.x + a4.y) + (a4.z + a4.w);
            }
        }
        __syncthreads();

        // ---- score via MFMA for both rows; K fragment shared per s-step
        const __bf16* kL = kb + (size_t)(li * B_ + b) * W_ * H_;
        for (int tile = wid; tile < (W_ + 15) / 16; tile += 4) {
            int w0t = tile * 16;
            int w = w0t + l15; if (w > W_ - 1) w = W_ - 1;
            int ls = s_ls[w], le = s_le[w];
            int i00 = min(max(ps0 - ls + MAXLEN_, 0), PEN_ - 1);
            int i01 = min(max(ps0 - le + MAXLEN_, 0), PEN_ - 1);
            int i02 = min(max(pev0 - ls + MAXLEN_, 0), PEN_ - 1);
            int i03 = min(max(pev0 - le + MAXLEN_, 0), PEN_ - 1);
            int i10 = min(max(ps1 - ls + MAXLEN_, 0), PEN_ - 1);
            int i11 = min(max(ps1 - le + MAXLEN_, 0), PEN_ - 1);
            int i12 = min(max(pev1 - ls + MAXLEN_, 0), PEN_ - 1);
            int i13 = min(max(pev1 - le + MAXLEN_, 0), PEN_ - 1);
            const __bf16* r00 = PEWb + (size_t)(0 * PEN_ + i00) * H_;
            const __bf16* r01 = PEWb + (size_t)(1 * PEN_ + i01) * H_;
            const __bf16* r02 = PEWb + (size_t)(2 * PEN_ + i02) * H_;
            const __bf16* r03 = PEWb + (size_t)(3 * PEN_ + i03) * H_;
            const __bf16* r10 = PEWb + (size_t)(0 * PEN_ + i10) * H_;
            const __bf16* r11 = PEWb + (size_t)(1 * PEN_ + i11) * H_;
            const __bf16* r12 = PEWb + (size_t)(2 * PEN_ + i12) * H_;
            const __bf16* r13 = PEWb + (size_t)(3 * PEN_ + i13) * H_;
            const __bf16* kr = kL + (size_t)w * H_;
            const __bf16* wrow0 = &s_wvecb[0][l15][0];
            const __bf16* wrow1 = &s_wvecb[1][l15][0];
            const __bf16* qrow0 = &s_qub[0][l15][0];
            const __bf16* qrow1 = &s_qub[1][l15][0];
            f32x4v acc0 = {0.f,0.f,0.f,0.f}, acc1 = {0.f,0.f,0.f,0.f};
            #pragma unroll 1
            for (int s = 0; s < 4; ++s) {
                int h0 = s * 32 + quad * 8;
                bf16x8 K = *(const bf16x8*)(kr + h0);
                // row 0
                {
                    bf16x8 t0 = *(const bf16x8*)(r00 + h0);
                    bf16x8 t1 = *(const bf16x8*)(r01 + h0);
                    bf16x8 t2 = *(const bf16x8*)(r02 + h0);
                    bf16x8 t3 = *(const bf16x8*)(r03 + h0);
                    bf16x8 A;
                    #pragma unroll
                    for (int j = 0; j < 8; ++j)
                        A[j] = (__bf16)fmaxf((float)t0[j] + (float)t1[j] + (float)t2[j] + (float)t3[j], 0.f);
                    bf16x8 Bf = *(const bf16x8*)(wrow0 + h0);
                    acc0 = __builtin_amdgcn_mfma_f32_16x16x32_bf16(A, Bf, acc0, 0, 0, 0);
                    bf16x8 Bq = *(const bf16x8*)(qrow0 + h0);
                    acc0 = __builtin_amdgcn_mfma_f32_16x16x32_bf16(K, Bq, acc0, 0, 0, 0);
                }
                // row 1
                {
                    bf16x8 t0 = *(const bf16x8*)(r10 + h0);
                    bf16x8 t1 = *(const bf16x8*)(r11 + h0);
                    bf16x8 t2 = *(const bf16x8*)(r12 + h0);
                    bf16x8 t3 = *(const bf16x8*)(r13 + h0);
                    bf16x8 A;
                    #pragma unroll
                    for (int j = 0; j < 8; ++j)
                        A[j] = (__bf16)fmaxf((float)t0[j] + (float)t1[j] + (float)t2[j] + (float)t3[j], 0.f);
                    bf16x8 Bf = *(const bf16x8*)(wrow1 + h0);
                    acc1 = __builtin_amdgcn_mfma_f32_16x16x32_bf16(A, Bf, acc1, 0, 0, 0);
                    bf16x8 Bq = *(const bf16x8*)(qrow1 + h0);
                    acc1 = __builtin_amdgcn_mfma_f32_16x16x32_bf16(K, Bq, acc1, 0, 0, 0);
                }
            }
            if (l15 < NH_) {
                float bt0 = s_bterm[0][l15], bt1 = s_bterm[1][l15];
                #pragma unroll
                for (int r = 0; r < 4; ++r) {
                    int wr = w0t + quad * 4 + r;
                    if (wr < W_) {
                        s_sc[0][l15][wr] = acc0[r] + bt0;
                        s_sc[1][l15][wr] = acc1[r] + bt1;
                    }
                }
            }
        }
        __syncthreads();

        // ---- softmax per head, per row
        {
            int n = t >> 5, ln_ = t & 31;
            #pragma unroll
            for (int r = 0; r < 2; ++r) {
                int cval = r ? cvalid1 : cvalid0;
                if (cval) {
                    float m = -INFINITY;
                    for (int w = ln_; w < wnum; w += 32) m = fmaxf(m, s_sc[r][n][w]);
                    #pragma unroll
                    for (int off = 16; off > 0; off >>= 1) m = fmaxf(m, __shfl_xor(m, off, 32));
                    float sum = 0.f;
                    for (int w = ln_; w < wnum; w += 32) sum += expf(s_sc[r][n][w] - m);
                    #pragma unroll
                    for (int off = 16; off > 0; off >>= 1) sum += __shfl_xor(sum, off, 32);
                    float inv = 1.f / sum;
                    for (int w = ln_; w < WP_; w += 32)
                        s_sc[r][n][w] = (w < wnum) ? expf(s_sc[r][n][w] - m) * inv : 0.f;
                } else {
                    for (int w = ln_; w < WP_; w += 32) s_sc[r][n][w] = 0.f;
                }
            }
        }
        __syncthreads();

        // ---- ctx = att @ v; v rows loaded once, used for both rows
        {
            int h = t & 127, half = t >> 7, n = h >> 4;
            const __bf16* vrow = vTb + ((size_t)(li * B_ + b) * H_ + h) * WP_;
            const float4* att0 = (const float4*)(s_sc[0][n]);
            const float4* att1 = (const float4*)(s_sc[1][n]);
            float4 a0 = {0,0,0,0}, a1 = {0,0,0,0};
            #pragma unroll 2
            for (int g = half * 19; g < half * 19 + 19; ++g) {
                bf16x8 vv = *(const bf16x8*)(vrow + 8 * g);
                float4 p00 = att0[2 * g], p01 = att0[2 * g + 1];
                float4 p10 = att1[2 * g], p11 = att1[2 * g + 1];
                float v0 = (float)vv[0], v1 = (float)vv[1], v2 = (float)vv[2], v3 = (float)vv[3];
                float v4 = (float)vv[4], v5 = (float)vv[5], v6 = (float)vv[6], v7 = (float)vv[7];
                a0.x += p00.x * v0 + p01.x * v4;
                a0.y += p00.y * v1 + p01.y * v5;
                a0.z += p00.z * v2 + p01.z * v6;
                a0.w += p00.w * v3 + p01.w * v7;
                a1.x += p10.x * v0 + p11.x * v4;
                a1.y += p10.y * v1 + p11.y * v5;
                a1.z += p10.z * v2 + p11.z * v6;
                a1.w += p10.w * v3 + p11.w * v7;
            }
            s_tmp[0][t] = (a0.x + a0.y) + (a0.z + a0.w);
            s_tmp[1][t] = (a1.x + a1.y) + (a1.z + a1.w);
        }
        __syncthreads();

        // ---- LN1: wave0 reduces row0, wave1 reduces row1 (3 barriers total)
        if (t < 128) {
            s_red[0][t] = s_tmp[0][t] + s_tmp[0][t + 128] + s_x[0][t];
        } else {
            int e = t - 128;
            s_red[1][e] = s_tmp[1][e] + s_tmp[1][e + 128] + s_x[1][e];
        }
        __syncthreads();
        if (t < 128) {
            int r = t >> 6, l = t & 63;
            float a = s_red[r][l], bb = s_red[r][l + 64];
            float s = a + bb, ss = a * a + bb * bb;
            #pragma unroll
            for (int off = 32; off > 0; off >>= 1) {
                s += __shfl_down(s, off);
                ss += __shfl_down(ss, off);
            }
            if (l == 0) {
                float mean = s * (1.f / 128.f);
                float var = ss * (1.f / 128.f) - mean * mean;
                s_red[r][128] = mean;
                s_red[r][129] = rsqrtf(var + 1e-5f);
            }
        }
        __syncthreads();
        if (t < H_) {
            float g1 = ln1_g[li * H_ + t], b1v = ln1_b[li * H_ + t];
            #pragma unroll
            for (int r = 0; r < 2; ++r)
                s_x[r][t] = (s_red[r][t] - s_red[r][128]) * s_red[r][129] * g1 + b1v;
        }
        __syncthreads();

        // ---- FF hidden: weight rows loaded once, used for both rows
        {
            const __bf16* W1l = W1T + (size_t)li * FF_ * H_;
            int u0 = t * 2;
            const __bf16* ra = W1l + (size_t)u0 * H_;
            const __bf16* rb = W1l + (size_t)(u0 + 1) * H_;
            const float4* x40 = (const float4*)s_x[0];
            const float4* x41 = (const float4*)s_x[1];
            float4 a00 = {0,0,0,0}, a01 = {0,0,0,0}, a10 = {0,0,0,0}, a11 = {0,0,0,0};
            #pragma unroll 2
            for (int g = 0; g < 16; ++g) {
                bf16x8 wa = *(const bf16x8*)(ra + 8 * g);
                bf16x8 wb = *(const bf16x8*)(rb + 8 * g);
                float4 xa0 = x40[2 * g], xa1 = x40[2 * g + 1];
                float4 xb0 = x41[2 * g], xb1 = x41[2 * g + 1];
                a00.x += xa0.x * (float)wa[0] + xa1.x * (float)wa[4];
                a00.y += xa0.y * (float)wa[1] + xa1.y * (float)wa[5];
                a00.z += xa0.z * (float)wa[2] + xa1.z * (float)wa[6];
                a00.w += xa0.w * (float)wa[3] + xa1.w * (float)wa[7];
                a01.x += xa0.x * (float)wb[0] + xa1.x * (float)wb[4];
                a01.y += xa0.y * (float)wb[1] + xa1.y * (float)wb[5];
                a01.z += xa0.z * (float)wb[2] + xa1.z * (float)wb[6];
                a01.w += xa0.w * (float)wb[3] + xa1.w * (float)wb[7];
                a10.x += xb0.x * (float)wa[0] + xb1.x * (float)wa[4];
                a10.y += xb0.y * (float)wa[1] + xb1.y * (float)wa[5];
                a10.z += xb0.z * (float)wa[2] + xb1.z * (float)wa[6];
                a10.w += xb0.w * (float)wa[3] + xb1.w * (float)wa[7];
                a11.x += xb0.x * (float)wb[0] + xb1.x * (float)wb[4];
                a11.y += xb0.y * (float)wb[1] + xb1.y * (float)wb[5];
                a11.z += xb0.z * (float)wb[2] + xb1.z * (float)wb[6];
                a11.w += xb0.w * (float)wb[3] + xb1.w * (float)wb[7];
            }
            float bb0 = b1[li * FF_ + u0], bb1 = b1[li * FF_ + u0 + 1];
            s_hid[0][u0]     = fmaxf((a00.x + a00.y) + (a00.z + a00.w) + bb0, 0.f);
            s_hid[0][u0 + 1] = fmaxf((a01.x + a01.y) + (a01.z + a01.w) + bb1, 0.f);
            s_hid[1][u0]     = fmaxf((a10.x + a10.y) + (a10.z + a10.w) + bb0, 0.f);
            s_hid[1][u0 + 1] = fmaxf((a11.x + a11.y) + (a11.z + a11.w) + bb1, 0.f);
        }
        __syncthreads();

        // ---- FF out: weight rows loaded once, used for both rows
        {
            int half = t >> 7, h = t & 127;
            const __bf16* wrow2 = W2T + ((size_t)li * H_ + h) * FF_ + half * 256;
            const float4* h40 = (const float4*)(s_hid[0] + half * 256);
            const float4* h41 = (const float4*)(s_hid[1] + half * 256);
            float4 a0 = {0,0,0,0}, a1 = {0,0,0,0};
            #pragma unroll 2
            for (int g = 0; g < 32; ++g) {
                bf16x8 wv = *(const bf16x8*)(wrow2 + 8 * g);
                float4 p00 = h40[2 * g], p01 = h40[2 * g + 1];
                float4 p10 = h41[2 * g], p11 = h41[2 * g + 1];
                float v0 = (float)wv[0], v1 = (float)wv[1], v2 = (float)wv[2], v3 = (float)wv[3];
                float v4 = (float)wv[4], v5 = (float)wv[5], v6 = (float)wv[6], v7 = (float)wv[7];
                a0.x += p00.x * v0 + p01.x * v4;
                a0.y += p00.y * v1 + p01.y * v5;
                a0.z += p00.z * v2 + p01.z * v6;
                a0.w += p00.w * v3 + p01.w * v7;
                a1.x += p10.x * v0 + p11.x * v4;
                a1.y += p10.y * v1 + p11.y * v5;
                a1.z += p10.z * v2 + p11.z * v6;
                a1.w += p10.w * v3 + p11.w * v7;
            }
            s_tmp[0][t] = (a0.x + a0.y) + (a0.z + a0.w);
            s_tmp[1][t] = (a1.x + a1.y) + (a1.z + a1.w);
        }
        __syncthreads();

        // ---- LN2
        if (t < 128) {
            s_red[0][t] = s_tmp[0][t] + s_tmp[0][t + 128] + b2[li * H_ + t] + s_x[0][t];
        } else {
            int e = t - 128;
            s_red[1][e] = s_tmp[1][e] + s_tmp[1][e + 128] + b2[li * H_ + e] + s_x[1][e];
        }
        __syncthreads();
        if (t < 128) {
            int r = t >> 6, l = t & 63;
            float a = s_red[r][l], bb = s_red[r][l + 64];
            float s = a + bb, ss = a * a + bb * bb;
            #pragma unroll
            for (int off = 32; off > 0; off >>= 1) {
                s += __shfl_down(s, off);
                ss += __shfl_down(ss, off);
            }
            if (l == 0) {
                float mean = s * (1.f / 128.f);
                float var = ss * (1.f / 128.f) - mean * mean;
                s_red[r][128] = mean;
                s_red[r][129] = rsqrtf(var + 1e-5f);
            }
        }
        __syncthreads();
        if (t < H_) {
            float g2 = ln2_g[li * H_ + t], b2v = ln2_b[li * H_ + t];
            #pragma unroll
            for (int r = 0; r < 2; ++r)
                s_x[r][t] = (s_red[r][t] - s_red[r][128]) * s_red[r][129] * g2 + b2v;
        }
        __syncthreads();
    }

    if (t < H_) {
        out[(b * C_ + c0) * H_ + t] = s_x[0][t];
        out[(b * C_ + c0 + CH_) * H_ + t] = s_x[1][t];
    }
}

extern "C" void kernel_launch(void* const* d_in, const int* in_sizes, int n_in,
                              void* d_out, int out_size, void* d_ws, size_t ws_size,
                              hipStream_t stream) {
    const float* chars  = (const float*)d_in[0];
    const float* words  = (const float*)d_in[1];
    const int* pos_s   = (const int*)d_in[2];
    const int* pos_e   = (const int*)d_in[3];
    const int* lex_s   = (const int*)d_in[4];
    const int* lex_e   = (const int*)d_in[5];
    const int* seq_len = (const int*)d_in[6];
    const int* lex_num = (const int*)d_in[7];
    const float* Wf  = (const float*)d_in[8];
    const float* bfv = (const float*)d_in[9];
    const float* Wq  = (const float*)d_in[10];
    const float* bq  = (const float*)d_in[11];
    const float* Wk  = (const float*)d_in[12];
    const float* bk  = (const float*)d_in[13];
    const float* Wv  = (const float*)d_in[14];
    const float* bv  = (const float*)d_in[15];
    const float* Wr  = (const float*)d_in[16];
    const float* br  = (const float*)d_in[17];
    const float* u_bias = (const float*)d_in[18];
    const float* v_bias = (const float*)d_in[19];
    const float* ln1_g  = (const float*)d_in[20];
    const float* ln1_b  = (const float*)d_in[21];
    const float* ln2_g  = (const float*)d_in[22];
    const float* ln2_b  = (const float*)d_in[23];
    const float* W1  = (const float*)d_in[24];
    const float* b1  = (const float*)d_in[25];
    const float* W2  = (const float*)d_in[26];
    const float* b2  = (const float*)d_in[27];

    __bf16* kb   = (__bf16*)d_ws;                      // L*B*W*H  = 307200 bf16
    __bf16* PEWb = kb + (size_t)L_ * B_ * W_ * H_;     // 262144 bf16
    __bf16* vTb  = PEWb + 4 * PEN_ * H_;               // L*B*H*WP = 311296 bf16
    __bf16* WrB  = vTb + (size_t)L_ * B_ * H_ * WP_;   // 32768 bf16
    __bf16* W1T  = WrB + L_ * H_ * H_;                 // 131072 bf16
    __bf16* W2T  = W1T + L_ * H_ * FF_;                // 131072 bf16

    prep_kernel<<<dim3(PREP_BLOCKS), dim3(128), 0, stream>>>(
        Wf, bfv, words, Wk, bk, Wv, bv, Wr, W1, W2,
        kb, PEWb, vTb, WrB, W1T, W2T);

    mega_kernel<<<dim3(B_ * CH_), dim3(256), 0, stream>>>(
        chars, pos_s, pos_e, lex_s, lex_e, seq_len, lex_num,
        Wq, bq, br, u_bias, v_bias,
        ln1_g, ln1_b, ln2_g, ln2_b, b1, b2,
        kb, PEWb, vTb, WrB, W1T, W2T, (float*)d_out);
}

// Round 19
// 267.741 us; speedup vs baseline: 1.2903x; 1.0094x over previous
//
#include <hip/hip_runtime.h>
#include <math.h>

#define B_ 4
#define C_ 200
#define CH_ 100          // rows per batch half; block r-pair = (c0, c0+100)
#define W_ 300
#define WP_ 304
#define H_ 128
#define NH_ 8
#define PH_ 16
#define FF_ 512
#define L_ 2
#define MAXLEN_ 200
#define PEN_ 512
#define WVS_ 136         // LDS B-matrix row stride (bf16)

typedef __bf16 bf16x8 __attribute__((ext_vector_type(8)));
typedef float f32x4v __attribute__((ext_vector_type(4)));

// prep grid segments (rebuilt: coalesced transposes, layer-merged kv)
#define SEG_PEW   512
#define SEG_KV    (SEG_PEW + B_ * W_)        // 512 + 1200 = 1712
#define SEG_WR    (SEG_KV + 256)             // 1968
#define SEG_W1T   (SEG_WR + 128)             // 2096 (2l x 4 j-tiles x 16 u-tiles)
#define PREP_BLOCKS (SEG_W1T + 128)          // 2224 (W2T: 2l x 16 u-tiles x 4 h-tiles)

// ---------------- prep: PEW | kv(both layers) | WrB copy | LDS-tiled transposes
__global__ __launch_bounds__(128) void prep_kernel(
        const float* __restrict__ Wf, const float* __restrict__ bfv,
        const float* __restrict__ words,
        const float* __restrict__ Wk, const float* __restrict__ bk,
        const float* __restrict__ Wv, const float* __restrict__ bv,
        const float* __restrict__ Wr, const float* __restrict__ W1,
        const float* __restrict__ W2,
        __bf16* __restrict__ kb, __bf16* __restrict__ PEWb, __bf16* __restrict__ vTb,
        __bf16* __restrict__ WrB, __bf16* __restrict__ W1T, __bf16* __restrict__ W2T) {
    __shared__ __align__(16) float s_row[H_];
    __shared__ float s_tile[32][33];             // transpose tile, pad 33
    int t = threadIdx.x;
    if (blockIdx.x < SEG_PEW) {
        int p = blockIdx.x;
        {
            int j = (t < 64) ? t : (t - 64);
            double f = exp(-(double)j * (log(10000.0) / 63.0));
            double a = (double)p * f;
            s_row[t] = (float)((t < 64) ? sin(a) : cos(a));
        }
        __syncthreads();
        float acc0 = 0.f, acc1 = 0.f, acc2 = 0.f, acc3 = 0.f;
        for (int j = 0; j < H_; ++j) {
            float xv = s_row[j];
            int row = j * H_ + t;
            acc0 += xv * Wf[0 * H_ * H_ + row];
            acc1 += xv * Wf[1 * H_ * H_ + row];
            acc2 += xv * Wf[2 * H_ * H_ + row];
            acc3 += xv * Wf[3 * H_ * H_ + row];
        }
        PEWb[(0 * PEN_ + p) * H_ + t] = (__bf16)(acc0 + bfv[t]);
        PEWb[(1 * PEN_ + p) * H_ + t] = (__bf16)acc1;
        PEWb[(2 * PEN_ + p) * H_ + t] = (__bf16)acc2;
        PEWb[(3 * PEN_ + p) * H_ + t] = (__bf16)acc3;
    } else if (blockIdx.x < SEG_KV) {
        int rem = blockIdx.x - SEG_PEW;      // b*W + w
        int bb = rem / W_, w = rem % W_;
        s_row[t] = words[rem * H_ + t];      // read once, used for both layers
        __syncthreads();
        const float4* row4 = (const float4*)s_row;
        #pragma unroll 1
        for (int li = 0; li < L_; ++li) {
            const float* wk = Wk + li * H_ * H_;
            const float* wv = Wv + li * H_ * H_;
            float4 ak = {0,0,0,0}, av = {0,0,0,0};
            #pragma unroll 2
            for (int g = 0; g < 32; ++g) {
                float4 x = row4[g];
                int j0 = 4 * g;
                ak.x += x.x * wk[(j0 + 0) * H_ + t];
                ak.y += x.y * wk[(j0 + 1) * H_ + t];
                ak.z += x.z * wk[(j0 + 2) * H_ + t];
                ak.w += x.w * wk[(j0 + 3) * H_ + t];
                av.x += x.x * wv[(j0 + 0) * H_ + t];
                av.y += x.y * wv[(j0 + 1) * H_ + t];
                av.z += x.z * wv[(j0 + 2) * H_ + t];
                av.w += x.w * wv[(j0 + 3) * H_ + t];
            }
            kb[(size_t)(li * B_ * W_ + rem) * H_ + t] =
                (__bf16)((ak.x + ak.y) + (ak.z + ak.w) + bk[li * H_ + t]);
            size_t vrow = ((size_t)(li * B_ + bb) * H_ + t) * WP_;
            vTb[vrow + w] = (__bf16)((av.x + av.y) + (av.z + av.w) + bv[li * H_ + t]);
            if (w == 0) {
                vTb[vrow + 300] = (__bf16)0.f; vTb[vrow + 301] = (__bf16)0.f;
                vTb[vrow + 302] = (__bf16)0.f; vTb[vrow + 303] = (__bf16)0.f;
            }
        }
    } else if (blockIdx.x < SEG_WR) {
        int i = (blockIdx.x - SEG_KV) * 128 + t;     // straight bf16 copy (coalesced)
        WrB[i] = (__bf16)Wr[i];
    } else if (blockIdx.x < SEG_W1T) {
        // W1T[l][u][j] = W1[l][j][u]; 32x32 LDS tile, coalesced read+write
        int blk = blockIdx.x - SEG_WR;               // 0..127
        int l = blk >> 6;
        int rem = blk & 63;
        int jt = rem >> 4;                           // 0..3  -> j0 = jt*32
        int ut = rem & 15;                           // 0..15 -> u0 = ut*32
        int r = t >> 5, cc = t & 31;
        #pragma unroll
        for (int k = 0; k < 8; ++k) {
            int j = jt * 32 + r + 4 * k;
            s_tile[r + 4 * k][cc] = W1[(l * H_ + j) * FF_ + ut * 32 + cc];
        }
        __syncthreads();
        int jl = t & 31, ul = t >> 5;
        #pragma unroll
        for (int k = 0; k < 8; ++k) {
            int u = ut * 32 + ul + 4 * k;
            W1T[((size_t)(l * FF_ + u)) * H_ + jt * 32 + jl] = (__bf16)s_tile[jl][ul + 4 * k];
        }
    } else {
        // W2T[l][h][u] = W2[l][u][h]; 32x32 LDS tile
        int blk = blockIdx.x - SEG_W1T;              // 0..127
        int l = blk >> 6;
        int rem = blk & 63;
        int ut = rem >> 2;                           // 0..15 -> u0 = ut*32
        int ht = rem & 3;                            // 0..3  -> h0 = ht*32
        int r = t >> 5, cc = t & 31;
        #pragma unroll
        for (int k = 0; k < 8; ++k) {
            int u = ut * 32 + r + 4 * k;
            s_tile[r + 4 * k][cc] = W2[(l * FF_ + u) * H_ + ht * 32 + cc];
        }
        __syncthreads();
        int ul = t & 31, hl = t >> 5;
        #pragma unroll
        for (int k = 0; k < 8; ++k) {
            int h = ht * 32 + hl + 4 * k;
            W2T[((size_t)(l * H_ + h)) * FF_ + ut * 32 + ul] = (__bf16)s_tile[ul][hl + 4 * k];
        }
    }
}

// ---------------- mega: one block per TWO rows (b,c0) and (b,c0+100); fp32 in/out
// (R18 verbatim — row pairing amortizes weight/k/v loads x2, halves barriers/row)
__global__ __launch_bounds__(256, 2) void mega_kernel(
    const float* __restrict__ chars,
    const int* __restrict__ pos_s, const int* __restrict__ pos_e,
    const int* __restrict__ lex_s, const int* __restrict__ lex_e,
    const int* __restrict__ seq_len, const int* __restrict__ lex_num,
    const float* __restrict__ Wq, const float* __restrict__ bq,
    const float* __restrict__ br,
    const float* __restrict__ u_bias, const float* __restrict__ v_bias,
    const float* __restrict__ ln1_g, const float* __restrict__ ln1_b,
    const float* __restrict__ ln2_g, const float* __restrict__ ln2_b,
    const float* __restrict__ b1, const float* __restrict__ b2,
    const __bf16* __restrict__ kb, const __bf16* __restrict__ PEWb,
    const __bf16* __restrict__ vTb, const __bf16* __restrict__ WrB,
    const __bf16* __restrict__ W1T, const __bf16* __restrict__ W2T,
    float* __restrict__ out) {

    __shared__ __align__(16) float s_x[2][H_], s_qv[2][H_];
    __shared__ __align__(16) __bf16 s_wvecb[2][16][WVS_];
    __shared__ __align__(16) __bf16 s_qub[2][16][WVS_];
    __shared__ float s_bterm[2][NH_];
    __shared__ __align__(16) float s_sc[2][NH_][WP_];
    __shared__ float s_red[2][132];
    __shared__ __align__(16) float s_hid[2][FF_];
    __shared__ float s_tmp[2][256];
    __shared__ int s_ls[W_], s_le[W_];

    int blk = blockIdx.x;               // 0..399
    int b = blk / CH_, c0 = blk % CH_;
    int t = threadIdx.x;
    int lane = t & 63;
    int wid = t >> 6;
    int l15 = lane & 15, quad = lane >> 4;

    if (t < H_) {
        s_x[0][t] = chars[(b * C_ + c0) * H_ + t];
        s_x[1][t] = chars[(b * C_ + c0 + CH_) * H_ + t];
    }
    for (int w = t; w < W_; w += 256) {
        s_ls[w] = lex_s[b * W_ + w];
        s_le[w] = lex_e[b * W_ + w];
    }
    for (int i = t; i < 2 * 8 * WVS_; i += 256) {
        int r = i / (8 * WVS_), rem = i % (8 * WVS_);
        s_wvecb[r][8 + rem / WVS_][rem % WVS_] = (__bf16)0.f;
    }
    for (int i = t; i < 2 * 16 * WVS_; i += 256) {
        int r = i / (16 * WVS_), rem = i % (16 * WVS_);
        s_qub[r][rem / WVS_][rem % WVS_] = (__bf16)0.f;
    }
    int ps0 = pos_s[b * C_ + c0],        pev0 = pos_e[b * C_ + c0];
    int ps1 = pos_s[b * C_ + c0 + CH_],  pev1 = pos_e[b * C_ + c0 + CH_];
    int slen = seq_len[b];
    int cvalid0 = (c0 < slen), cvalid1 = (c0 + CH_ < slen);
    int wnum = lex_num[b];
    __syncthreads();

    for (int li = 0; li < L_; ++li) {
        // ---- q projection
        {
            int half = t >> 7, h = t & 127;
            const float* WqL = Wq + li * H_ * H_;
            const float4* x40 = (const float4*)s_x[0];
            const float4* x41 = (const float4*)s_x[1];
            float4 a0 = {0,0,0,0}, a1 = {0,0,0,0};
            #pragma unroll 2
            for (int g = half * 16; g < half * 16 + 16; ++g) {
                float4 xa = x40[g], xb = x41[g];
                int j0 = 4 * g;
                float w0 = WqL[(j0 + 0) * H_ + h], w1 = WqL[(j0 + 1) * H_ + h];
                float w2 = WqL[(j0 + 2) * H_ + h], w3 = WqL[(j0 + 3) * H_ + h];
                a0.x += xa.x * w0; a0.y += xa.y * w1; a0.z += xa.z * w2; a0.w += xa.w * w3;
                a1.x += xb.x * w0; a1.y += xb.y * w1; a1.z += xb.z * w2; a1.w += xb.w * w3;
            }
            s_tmp[0][t] = (a0.x + a0.y) + (a0.z + a0.w);
            s_tmp[1][t] = (a1.x + a1.y) + (a1.z + a1.w);
        }
        __syncthreads();
        if (t < H_) {
            #pragma unroll
            for (int r = 0; r < 2; ++r) {
                float acc = s_tmp[r][t] + s_tmp[r][t + 128] + bq[li * H_ + t];
                s_qub[r][t >> 4][t] = (__bf16)(acc + u_bias[li * H_ + t]);
                s_qv[r][t] = acc + v_bias[li * H_ + t];
            }
        }
        __syncthreads();

        // ---- wvec + bterm
        if (t < H_) {
            const __bf16* WrRow = WrB + li * H_ * H_ + t * H_;
            #pragma unroll 2
            for (int n = 0; n < NH_; ++n) {
                bf16x8 w0 = *(const bf16x8*)(WrRow + n * PH_);
                bf16x8 w1 = *(const bf16x8*)(WrRow + n * PH_ + 8);
                #pragma unroll
                for (int r = 0; r < 2; ++r) {
                    const float4* qv4 = (const float4*)(s_qv[r] + n * PH_);
                    float4 q0 = qv4[0], q1 = qv4[1], q2 = qv4[2], q3 = qv4[3];
                    float4 a4;
                    a4.x = (float)w0[0] * q0.x + (float)w1[0] * q2.x;
                    a4.y = (float)w0[1] * q0.y + (float)w1[1] * q2.y;
                    a4.z = (float)w0[2] * q0.z + (float)w1[2] * q2.z;
                    a4.w = (float)w0[3] * q0.w + (float)w1[3] * q2.w;
                    a4.x += (float)w0[4] * q1.x + (float)w1[4] * q3.x;
                    a4.y += (float)w0[5] * q1.y + (float)w1[5] * q3.y;
                    a4.z += (float)w0[6] * q1.z + (float)w1[6] * q3.z;
                    a4.w += (float)w0[7] * q1.w + (float)w1[7] * q3.w;
                    s_wvecb[r][n][t] = (__bf16)((a4.x + a4.y) + (a4.z + a4.w));
                }
            }
        } else if (t < H_ + NH_) {
            int n = t - H_;
            const float4* br4 = (const float4*)(br + li * H_ + n * PH_);
            float4 b0 = br4[0], b1v = br4[1], b2v = br4[2], b3v = br4[3];
            #pragma unroll
            for (int r = 0; r < 2; ++r) {
                const float4* qv4 = (const float4*)(s_qv[r] + n * PH_);
                float4 q0 = qv4[0], q1 = qv4[1], q2 = qv4[2], q3 = qv4[3];
                float4 a4;
                a4.x = b0.x * q0.x + b2v.x * q2.x;
                a4.y = b0.y * q0.y + b2v.y * q2.y;
                a4.z = b0.z * q0.z + b2v.z * q2.z;
                a4.w = b0.w * q0.w + b2v.w * q2.w;
                a4.x += b1v.x * q1.x + b3v.x * q3.x;
                a4.y += b1v.y * q1.y + b3v.y * q3.y;
                a4.z += b1v.z * q1.z + b3v.z * q3.z;
                a4.w += b1v.w * q1.w + b3v.w * q3.w;
                s_bterm[r][n] = (a4.x + a4.y) + (a4.z + a4.w);
            }
        }
        __syncthreads();

        // ---- score via MFMA for both rows; K fragment shared per s-step
        const __bf16* kL = kb + (size_t)(li * B_ + b) * W_ * H_;
        for (int tile = wid; tile < (W_ + 15) / 16; tile += 4) {
            int w0t = tile * 16;
            int w = w0t + l15; if (w > W_ - 1) w = W_ - 1;
            int ls = s_ls[w], le = s_le[w];
            int i00 = min(max(ps0 - ls + MAXLEN_, 0), PEN_ - 1);
            int i01 = min(max(ps0 - le + MAXLEN_, 0), PEN_ - 1);
            int i02 = min(max(pev0 - ls + MAXLEN_, 0), PEN_ - 1);
            int i03 = min(max(pev0 - le + MAXLEN_, 0), PEN_ - 1);
            int i10 = min(max(ps1 - ls + MAXLEN_, 0), PEN_ - 1);
            int i11 = min(max(ps1 - le + MAXLEN_, 0), PEN_ - 1);
            int i12 = min(max(pev1 - ls + MAXLEN_, 0), PEN_ - 1);
            int i13 = min(max(pev1 - le + MAXLEN_, 0), PEN_ - 1);
            const __bf16* r00 = PEWb + (size_t)(0 * PEN_ + i00) * H_;
            const __bf16* r01 = PEWb + (size_t)(1 * PEN_ + i01) * H_;
            const __bf16* r02 = PEWb + (size_t)(2 * PEN_ + i02) * H_;
            const __bf16* r03 = PEWb + (size_t)(3 * PEN_ + i03) * H_;
            const __bf16* r10 = PEWb + (size_t)(0 * PEN_ + i10) * H_;
            const __bf16* r11 = PEWb + (size_t)(1 * PEN_ + i11) * H_;
            const __bf16* r12 = PEWb + (size_t)(2 * PEN_ + i12) * H_;
            const __bf16* r13 = PEWb + (size_t)(3 * PEN_ + i13) * H_;
            const __bf16* kr = kL + (size_t)w * H_;
            const __bf16* wrow0 = &s_wvecb[0][l15][0];
            const __bf16* wrow1 = &s_wvecb[1][l15][0];
            const __bf16* qrow0 = &s_qub[0][l15][0];
            const __bf16* qrow1 = &s_qub[1][l15][0];
            f32x4v acc0 = {0.f,0.f,0.f,0.f}, acc1 = {0.f,0.f,0.f,0.f};
            #pragma unroll 1
            for (int s = 0; s < 4; ++s) {
                int h0 = s * 32 + quad * 8;
                bf16x8 K = *(const bf16x8*)(kr + h0);
                {
                    bf16x8 t0 = *(const bf16x8*)(r00 + h0);
                    bf16x8 t1 = *(const bf16x8*)(r01 + h0);
                    bf16x8 t2 = *(const bf16x8*)(r02 + h0);
                    bf16x8 t3 = *(const bf16x8*)(r03 + h0);
                    bf16x8 A;
                    #pragma unroll
                    for (int j = 0; j < 8; ++j)
                        A[j] = (__bf16)fmaxf((float)t0[j] + (float)t1[j] + (float)t2[j] + (float)t3[j], 0.f);
                    bf16x8 Bf = *(const bf16x8*)(wrow0 + h0);
                    acc0 = __builtin_amdgcn_mfma_f32_16x16x32_bf16(A, Bf, acc0, 0, 0, 0);
                    bf16x8 Bq = *(const bf16x8*)(qrow0 + h0);
                    acc0 = __builtin_amdgcn_mfma_f32_16x16x32_bf16(K, Bq, acc0, 0, 0, 0);
                }
                {
                    bf16x8 t0 = *(const bf16x8*)(r10 + h0);
                    bf16x8 t1 = *(const bf16x8*)(r11 + h0);
                    bf16x8 t2 = *(const bf16x8*)(r12 + h0);
                    bf16x8 t3 = *(const bf16x8*)(r13 + h0);
                    bf16x8 A;
                    #pragma unroll
                    for (int j = 0; j < 8; ++j)
                        A[j] = (__bf16)fmaxf((float)t0[j] + (float)t1[j] + (float)t2[j] + (float)t3[j], 0.f);
                    bf16x8 Bf = *(const bf16x8*)(wrow1 + h0);
                    acc1 = __builtin_amdgcn_mfma_f32_16x16x32_bf16(A, Bf, acc1, 0, 0, 0);
                    bf16x8 Bq = *(const bf16x8*)(qrow1 + h0);
                    acc1 = __builtin_amdgcn_mfma_f32_16x16x32_bf16(K, Bq, acc1, 0, 0, 0);
                }
            }
            if (l15 < NH_) {
                float bt0 = s_bterm[0][l15], bt1 = s_bterm[1][l15];
                #pragma unroll
                for (int r = 0; r < 4; ++r) {
                    int wr = w0t + quad * 4 + r;
                    if (wr < W_) {
                        s_sc[0][l15][wr] = acc0[r] + bt0;
                        s_sc[1][l15][wr] = acc1[r] + bt1;
                    }
                }
            }
        }
        __syncthreads();

        // ---- softmax per head, per row
        {
            int n = t >> 5, ln_ = t & 31;
            #pragma unroll
            for (int r = 0; r < 2; ++r) {
                int cval = r ? cvalid1 : cvalid0;
                if (cval) {
                    float m = -INFINITY;
                    for (int w = ln_; w < wnum; w += 32) m = fmaxf(m, s_sc[r][n][w]);
                    #pragma unroll
                    for (int off = 16; off > 0; off >>= 1) m = fmaxf(m, __shfl_xor(m, off, 32));
                    float sum = 0.f;
                    for (int w = ln_; w < wnum; w += 32) sum += expf(s_sc[r][n][w] - m);
                    #pragma unroll
                    for (int off = 16; off > 0; off >>= 1) sum += __shfl_xor(sum, off, 32);
                    float inv = 1.f / sum;
                    for (int w = ln_; w < WP_; w += 32)
                        s_sc[r][n][w] = (w < wnum) ? expf(s_sc[r][n][w] - m) * inv : 0.f;
                } else {
                    for (int w = ln_; w < WP_; w += 32) s_sc[r][n][w] = 0.f;
                }
            }
        }
        __syncthreads();

        // ---- ctx = att @ v
        {
            int h = t & 127, half = t >> 7, n = h >> 4;
            const __bf16* vrow = vTb + ((size_t)(li * B_ + b) * H_ + h) * WP_;
            const float4* att0 = (const float4*)(s_sc[0][n]);
            const float4* att1 = (const float4*)(s_sc[1][n]);
            float4 a0 = {0,0,0,0}, a1 = {0,0,0,0};
            #pragma unroll 2
            for (int g = half * 19; g < half * 19 + 19; ++g) {
                bf16x8 vv = *(const bf16x8*)(vrow + 8 * g);
                float4 p00 = att0[2 * g], p01 = att0[2 * g + 1];
                float4 p10 = att1[2 * g], p11 = att1[2 * g + 1];
                float v0 = (float)vv[0], v1 = (float)vv[1], v2 = (float)vv[2], v3 = (float)vv[3];
                float v4 = (float)vv[4], v5 = (float)vv[5], v6 = (float)vv[6], v7 = (float)vv[7];
                a0.x += p00.x * v0 + p01.x * v4;
                a0.y += p00.y * v1 + p01.y * v5;
                a0.z += p00.z * v2 + p01.z * v6;
                a0.w += p00.w * v3 + p01.w * v7;
                a1.x += p10.x * v0 + p11.x * v4;
                a1.y += p10.y * v1 + p11.y * v5;
                a1.z += p10.z * v2 + p11.z * v6;
                a1.w += p10.w * v3 + p11.w * v7;
            }
            s_tmp[0][t] = (a0.x + a0.y) + (a0.z + a0.w);
            s_tmp[1][t] = (a1.x + a1.y) + (a1.z + a1.w);
        }
        __syncthreads();

        // ---- LN1
        if (t < 128) {
            s_red[0][t] = s_tmp[0][t] + s_tmp[0][t + 128] + s_x[0][t];
        } else {
            int e = t - 128;
            s_red[1][e] = s_tmp[1][e] + s_tmp[1][e + 128] + s_x[1][e];
        }
        __syncthreads();
        if (t < 128) {
            int r = t >> 6, l = t & 63;
            float a = s_red[r][l], bb = s_red[r][l + 64];
            float s = a + bb, ss = a * a + bb * bb;
            #pragma unroll
            for (int off = 32; off > 0; off >>= 1) {
                s += __shfl_down(s, off);
                ss += __shfl_down(ss, off);
            }
            if (l == 0) {
                float mean = s * (1.f / 128.f);
                float var = ss * (1.f / 128.f) - mean * mean;
                s_red[r][128] = mean;
                s_red[r][129] = rsqrtf(var + 1e-5f);
            }
        }
        __syncthreads();
        if (t < H_) {
            float g1 = ln1_g[li * H_ + t], b1v = ln1_b[li * H_ + t];
            #pragma unroll
            for (int r = 0; r < 2; ++r)
                s_x[r][t] = (s_red[r][t] - s_red[r][128]) * s_red[r][129] * g1 + b1v;
        }
        __syncthreads();

        // ---- FF hidden
        {
            const __bf16* W1l = W1T + (size_t)li * FF_ * H_;
            int u0 = t * 2;
            const __bf16* ra = W1l + (size_t)u0 * H_;
            const __bf16* rb = W1l + (size_t)(u0 + 1) * H_;
            const float4* x40 = (const float4*)s_x[0];
            const float4* x41 = (const float4*)s_x[1];
            float4 a00 = {0,0,0,0}, a01 = {0,0,0,0}, a10 = {0,0,0,0}, a11 = {0,0,0,0};
            #pragma unroll 2
            for (int g = 0; g < 16; ++g) {
                bf16x8 wa = *(const bf16x8*)(ra + 8 * g);
                bf16x8 wb = *(const bf16x8*)(rb + 8 * g);
                float4 xa0 = x40[2 * g], xa1 = x40[2 * g + 1];
                float4 xb0 = x41[2 * g], xb1 = x41[2 * g + 1];
                a00.x += xa0.x * (float)wa[0] + xa1.x * (float)wa[4];
                a00.y += xa0.y * (float)wa[1] + xa1.y * (float)wa[5];
                a00.z += xa0.z * (float)wa[2] + xa1.z * (float)wa[6];
                a00.w += xa0.w * (float)wa[3] + xa1.w * (float)wa[7];
                a01.x += xa0.x * (float)wb[0] + xa1.x * (float)wb[4];
                a01.y += xa0.y * (float)wb[1] + xa1.y * (float)wb[5];
                a01.z += xa0.z * (float)wb[2] + xa1.z * (float)wb[6];
                a01.w += xa0.w * (float)wb[3] + xa1.w * (float)wb[7];
                a10.x += xb0.x * (float)wa[0] + xb1.x * (float)wa[4];
                a10.y += xb0.y * (float)wa[1] + xb1.y * (float)wa[5];
                a10.z += xb0.z * (float)wa[2] + xb1.z * (float)wa[6];
                a10.w += xb0.w * (float)wa[3] + xb1.w * (float)wa[7];
                a11.x += xb0.x * (float)wb[0] + xb1.x * (float)wb[4];
                a11.y += xb0.y * (float)wb[1] + xb1.y * (float)wb[5];
                a11.z += xb0.z * (float)wb[2] + xb1.z * (float)wb[6];
                a11.w += xb0.w * (float)wb[3] + xb1.w * (float)wb[7];
            }
            float bb0 = b1[li * FF_ + u0], bb1 = b1[li * FF_ + u0 + 1];
            s_hid[0][u0]     = fmaxf((a00.x + a00.y) + (a00.z + a00.w) + bb0, 0.f);
            s_hid[0][u0 + 1] = fmaxf((a01.x + a01.y) + (a01.z + a01.w) + bb1, 0.f);
            s_hid[1][u0]     = fmaxf((a10.x + a10.y) + (a10.z + a10.w) + bb0, 0.f);
            s_hid[1][u0 + 1] = fmaxf((a11.x + a11.y) + (a11.z + a11.w) + bb1, 0.f);
        }
        __syncthreads();

        // ---- FF out
        {
            int half = t >> 7, h = t & 127;
            const __bf16* wrow2 = W2T + ((size_t)li * H_ + h) * FF_ + half * 256;
            const float4* h40 = (const float4*)(s_hid[0] + half * 256);
            const float4* h41 = (const float4*)(s_hid[1] + half * 256);
            float4 a0 = {0,0,0,0}, a1 = {0,0,0,0};
            #pragma unroll 2
            for (int g = 0; g < 32; ++g) {
                bf16x8 wv = *(const bf16x8*)(wrow2 + 8 * g);
                float4 p00 = h40[2 * g], p01 = h40[2 * g + 1];
                float4 p10 = h41[2 * g], p11 = h41[2 * g + 1];
                float v0 = (float)wv[0], v1 = (float)wv[1], v2 = (float)wv[2], v3 = (float)wv[3];
                float v4 = (float)wv[4], v5 = (float)wv[5], v6 = (float)wv[6], v7 = (float)wv[7];
                a0.x += p00.x * v0 + p01.x * v4;
                a0.y += p00.y * v1 + p01.y * v5;
                a0.z += p00.z * v2 + p01.z * v6;
                a0.w += p00.w * v3 + p01.w * v7;
                a1.x += p10.x * v0 + p11.x * v4;
                a1.y += p10.y * v1 + p11.y * v5;
                a1.z += p10.z * v2 + p11.z * v6;
                a1.w += p10.w * v3 + p11.w * v7;
            }
            s_tmp[0][t] = (a0.x + a0.y) + (a0.z + a0.w);
            s_tmp[1][t] = (a1.x + a1.y) + (a1.z + a1.w);
        }
        __syncthreads();

        // ---- LN2
        if (t < 128) {
            s_red[0][t] = s_tmp[0][t] + s_tmp[0][t + 128] + b2[li * H_ + t] + s_x[0][t];
        } else {
            int e = t - 128;
            s_red[1][e] = s_tmp[1][e] + s_tmp[1][e + 128] + b2[li * H_ + e] + s_x[1][e];
        }
        __syncthreads();
        if (t < 128) {
            int r = t >> 6, l = t & 63;
            float a = s_red[r][l], bb = s_red[r][l + 64];
            float s = a + bb, ss = a * a + bb * bb;
            #pragma unroll
            for (int off = 32; off > 0; off >>= 1) {
                s += __shfl_down(s, off);
                ss += __shfl_down(ss, off);
            }
            if (l == 0) {
                float mean = s * (1.f / 128.f);
                float var = ss * (1.f / 128.f) - mean * mean;
                s_red[r][128] = mean;
                s_red[r][129] = rsqrtf(var + 1e-5f);
            }
        }
        __syncthreads();
        if (t < H_) {
            float g2 = ln2_g[li * H_ + t], b2v = ln2_b[li * H_ + t];
            #pragma unroll
            for (int r = 0; r < 2; ++r)
                s_x[r][t] = (s_red[r][t] - s_red[r][128]) * s_red[r][129] * g2 + b2v;
        }
        __syncthreads();
    }

    if (t < H_) {
        out[(b * C_ + c0) * H_ + t] = s_x[0][t];
        out[(b * C_ + c0 + CH_) * H_ + t] = s_x[1][t];
    }
}

extern "C" void kernel_launch(void* const* d_in, const int* in_sizes, int n_in,
                              void* d_out, int out_size, void* d_ws, size_t ws_size,
                              hipStream_t stream) {
    const float* chars  = (const float*)d_in[0];
    const float* words  = (const float*)d_in[1];
    const int* pos_s   = (const int*)d_in[2];
    const int* pos_e   = (const int*)d_in[3];
    const int* lex_s   = (const int*)d_in[4];
    const int* lex_e   = (const int*)d_in[5];
    const int* seq_len = (const int*)d_in[6];
    const int* lex_num = (const int*)d_in[7];
    const float* Wf  = (const float*)d_in[8];
    const float* bfv = (const float*)d_in[9];
    const float* Wq  = (const float*)d_in[10];
    const float* bq  = (const float*)d_in[11];
    const float* Wk  = (const float*)d_in[12];
    const float* bk  = (const float*)d_in[13];
    const float* Wv  = (const float*)d_in[14];
    const float* bv  = (const float*)d_in[15];
    const float* Wr  = (const float*)d_in[16];
    const float* br  = (const float*)d_in[17];
    const float* u_bias = (const float*)d_in[18];
    const float* v_bias = (const float*)d_in[19];
    const float* ln1_g  = (const float*)d_in[20];
    const float* ln1_b  = (const float*)d_in[21];
    const float* ln2_g  = (const float*)d_in[22];
    const float* ln2_b  = (const float*)d_in[23];
    const float* W1  = (const float*)d_in[24];
    const float* b1  = (const float*)d_in[25];
    const float* W2  = (const float*)d_in[26];
    const float* b2  = (const float*)d_in[27];

    __bf16* kb   = (__bf16*)d_ws;                      // L*B*W*H  = 307200 bf16
    __bf16* PEWb = kb + (size_t)L_ * B_ * W_ * H_;     // 262144 bf16
    __bf16* vTb  = PEWb + 4 * PEN_ * H_;               // L*B*H*WP = 311296 bf16
    __bf16* WrB  = vTb + (size_t)L_ * B_ * H_ * WP_;   // 32768 bf16
    __bf16* W1T  = WrB + L_ * H_ * H_;                 // 131072 bf16
    __bf16* W2T  = W1T + L_ * H_ * FF_;                // 131072 bf16

    prep_kernel<<<dim3(PREP_BLOCKS), dim3(128), 0, stream>>>(
        Wf, bfv, words, Wk, bk, Wv, bv, Wr, W1, W2,
        kb, PEWb, vTb, WrB, W1T, W2T);

    mega_kernel<<<dim3(B_ * CH_), dim3(256), 0, stream>>>(
        chars, pos_s, pos_e, lex_s, lex_e, seq_len, lex_num,
        Wq, bq, br, u_bias, v_bias,
        ln1_g, ln1_b, ln2_g, ln2_b, b1, b2,
        kb, PEWb, vTb, WrB, W1T, W2T, (float*)d_out);
}